// Round 4
// baseline (1064.440 us; speedup 1.0000x reference)
//
#include <hip/hip_runtime.h>
#include <math.h>

#define N_NODES 50000
#define N_EDGES 800000
#define F_IN 64
#define D 128
#define NLAYER 3
#define B_GRAPHS 8
#define G 8                 // nodes per block (4 waves x 2 nodes)
#define SCAN_B 512
#define NPART ((N_NODES + SCAN_B - 1) / SCAN_B)   // 98

__device__ __forceinline__ float gelu_exact(float x) {
    return 0.5f * x * (1.0f + erff(x * 0.7071067811865476f));
}

// wave-wide (64-lane) sum, result in all lanes
__device__ __forceinline__ float wave_sum(float v) {
    #pragma unroll
    for (int o = 32; o >= 1; o >>= 1) v += __shfl_xor(v, o);
    return v;
}

// mean / inv-std over a 128-wide row held as float2 per lane (one wave)
__device__ __forceinline__ void wave_meanvar(float vx, float vy, float& mean, float& inv_std) {
    float s = vx + vy;
    float q = vx * vx + vy * vy;
    #pragma unroll
    for (int o = 32; o >= 1; o >>= 1) { s += __shfl_xor(s, o); q += __shfl_xor(q, o); }
    mean = s * (1.0f / D);
    float var = q * (1.0f / D) - mean * mean;
    inv_std = rsqrtf(var + 1e-5f);
}

// ---------------- CSR build ----------------

__global__ void zero_int_kernel(int* __restrict__ p, int n) {
    int i = blockIdx.x * blockDim.x + threadIdx.x;
    int stride = gridDim.x * blockDim.x;
    for (; i < n; i += stride) p[i] = 0;
}

__global__ void degree_kernel(const int* __restrict__ dst, int* __restrict__ deg) {
    int e = blockIdx.x * blockDim.x + threadIdx.x;
    if (e < N_EDGES) atomicAdd(&deg[dst[e]], 1);
}

// phase 1: per-block sums of deg
__global__ __launch_bounds__(SCAN_B) void scan_partials_kernel(const int* __restrict__ deg,
                                                               int* __restrict__ partials) {
    __shared__ int wsum[8];
    int tid = threadIdx.x;
    int lane = tid & 63, wave = tid >> 6;
    int i = blockIdx.x * SCAN_B + tid;
    int v = (i < N_NODES) ? deg[i] : 0;
    #pragma unroll
    for (int o = 32; o >= 1; o >>= 1) v += __shfl_xor(v, o);
    if (lane == 0) wsum[wave] = v;
    __syncthreads();
    if (tid == 0) {
        int t = 0;
        #pragma unroll
        for (int w = 0; w < 8; ++w) t += wsum[w];
        partials[blockIdx.x] = t;
    }
}

// phase 2: single small block — exclusive scan of the 98 partials (in place) + total
__global__ void scan_offsets_kernel(int* __restrict__ partials, int* __restrict__ row_ptr) {
    __shared__ int wtot[2];
    int tid = threadIdx.x;          // 128 threads, 2 waves
    int lane = tid & 63, wave = tid >> 6;
    int v = (tid < NPART) ? partials[tid] : 0;
    int x = v;
    #pragma unroll
    for (int o = 1; o < 64; o <<= 1) { int nb = __shfl_up(x, o); if (lane >= o) x += nb; }
    if (lane == 63) wtot[wave] = x;
    __syncthreads();
    if (wave == 1) x += wtot[0];
    if (tid < NPART) partials[tid] = x - v;       // exclusive
    if (tid == 127) row_ptr[N_NODES] = x;         // grand total
}

// phase 3: per-block scan + global offset -> row_ptr / cursor
__global__ __launch_bounds__(SCAN_B) void scan_apply_kernel(const int* __restrict__ deg,
        const int* __restrict__ partials, int* __restrict__ row_ptr, int* __restrict__ cursor) {
    __shared__ int wsum[8];
    int tid = threadIdx.x;
    int lane = tid & 63, wave = tid >> 6;
    int i = blockIdx.x * SCAN_B + tid;
    int v = (i < N_NODES) ? deg[i] : 0;
    int x = v;
    #pragma unroll
    for (int o = 1; o < 64; o <<= 1) { int nb = __shfl_up(x, o); if (lane >= o) x += nb; }
    if (lane == 63) wsum[wave] = x;
    __syncthreads();
    int waveoff = 0;
    #pragma unroll
    for (int w = 0; w < 8; ++w) waveoff += (w < wave) ? wsum[w] : 0;
    int excl = partials[blockIdx.x] + waveoff + x - v;
    if (i < N_NODES) { row_ptr[i] = excl; cursor[i] = excl; }
}

__global__ void fill_kernel(const int* __restrict__ src, const int* __restrict__ dst,
                            int* __restrict__ cursor, int* __restrict__ csr) {
    int e = blockIdx.x * blockDim.x + threadIdx.x;
    if (e < N_EDGES) {
        int t = dst[e];
        int pos = atomicAdd(&cursor[t], 1);
        csr[pos] = src[e];
    }
}

// ---------------- node kernels (wave = 2 nodes, lane = 2 dims) ----------------

// mean-neighbor gather for one node, 2 dims per lane, 4-way unrolled for ILP
__device__ __forceinline__ float2 gather_mean(const float* __restrict__ h_in,
                                              const int* __restrict__ csr,
                                              int beg, int end, int d0) {
    float ax0 = 0.f, ay0 = 0.f, ax1 = 0.f, ay1 = 0.f;
    float ax2 = 0.f, ay2 = 0.f, ax3 = 0.f, ay3 = 0.f;
    int e = beg;
    for (; e + 3 < end; e += 4) {
        int s0 = csr[e], s1 = csr[e + 1], s2 = csr[e + 2], s3 = csr[e + 3];
        float2 v0 = *(const float2*)&h_in[(size_t)s0 * D + d0];
        float2 v1 = *(const float2*)&h_in[(size_t)s1 * D + d0];
        float2 v2 = *(const float2*)&h_in[(size_t)s2 * D + d0];
        float2 v3 = *(const float2*)&h_in[(size_t)s3 * D + d0];
        ax0 += v0.x; ay0 += v0.y;
        ax1 += v1.x; ay1 += v1.y;
        ax2 += v2.x; ay2 += v2.y;
        ax3 += v3.x; ay3 += v3.y;
    }
    for (; e < end; ++e) {
        float2 v = *(const float2*)&h_in[(size_t)csr[e] * D + d0];
        ax0 += v.x; ay0 += v.y;
    }
    float inv = 1.0f / fmaxf((float)(end - beg), 1.0f);
    return make_float2((ax0 + ax1 + ax2 + ax3) * inv, (ay0 + ay1 + ay2 + ay3) * inv);
}

// h = gelu(ln(x @ w_in + b_in))
__global__ __launch_bounds__(256) void input_proj_v2(
        const float* __restrict__ x, const float* __restrict__ w,
        const float* __restrict__ b, const float* __restrict__ gam,
        const float* __restrict__ bet, float* __restrict__ h) {
    __shared__ float xs[G][F_IN];
    int tid = threadIdx.x;
    int wave = tid >> 6, lane = tid & 63;
    int d0 = lane << 1;
    int n0 = blockIdx.x * G;
    int gA = wave * 2, gB = gA + 1;
    int nA = n0 + gA, nB = n0 + gB;

    xs[gA][lane] = x[(size_t)nA * F_IN + lane];
    xs[gB][lane] = x[(size_t)nB * F_IN + lane];
    __syncthreads();

    float2 bb = *(const float2*)&b[d0];
    float aAx = bb.x, aAy = bb.y, aBx = bb.x, aBy = bb.y;
    #pragma unroll 4
    for (int k = 0; k < F_IN; k += 4) {
        float4 cA = *(const float4*)&xs[gA][k];
        float4 cB = *(const float4*)&xs[gB][k];
        float2 w0 = *(const float2*)&w[(k + 0) * D + d0];
        float2 w1 = *(const float2*)&w[(k + 1) * D + d0];
        float2 w2 = *(const float2*)&w[(k + 2) * D + d0];
        float2 w3 = *(const float2*)&w[(k + 3) * D + d0];
        aAx = fmaf(cA.x, w0.x, aAx); aAy = fmaf(cA.x, w0.y, aAy);
        aAx = fmaf(cA.y, w1.x, aAx); aAy = fmaf(cA.y, w1.y, aAy);
        aAx = fmaf(cA.z, w2.x, aAx); aAy = fmaf(cA.z, w2.y, aAy);
        aAx = fmaf(cA.w, w3.x, aAx); aAy = fmaf(cA.w, w3.y, aAy);
        aBx = fmaf(cB.x, w0.x, aBx); aBy = fmaf(cB.x, w0.y, aBy);
        aBx = fmaf(cB.y, w1.x, aBx); aBy = fmaf(cB.y, w1.y, aBy);
        aBx = fmaf(cB.z, w2.x, aBx); aBy = fmaf(cB.z, w2.y, aBy);
        aBx = fmaf(cB.w, w3.x, aBx); aBy = fmaf(cB.w, w3.y, aBy);
    }
    float2 gg = *(const float2*)&gam[d0];
    float2 bt = *(const float2*)&bet[d0];
    float m, istd;
    wave_meanvar(aAx, aAy, m, istd);
    float2 oA = make_float2(gelu_exact((aAx - m) * istd * gg.x + bt.x),
                            gelu_exact((aAy - m) * istd * gg.y + bt.y));
    *(float2*)&h[(size_t)nA * D + d0] = oA;
    wave_meanvar(aBx, aBy, m, istd);
    float2 oB = make_float2(gelu_exact((aBx - m) * istd * gg.x + bt.x),
                            gelu_exact((aBy - m) * istd * gg.y + bt.y));
    *(float2*)&h[(size_t)nB * D + d0] = oB;
}

// fused: CSR mean-gather + [h,agg]@W + gelu + LN1 + LN2 (+gelu+residual); ping-pong buffers
__global__ __launch_bounds__(256) void gnn_layer_v2(
        const float* __restrict__ h_in, float* __restrict__ h_out,
        const int* __restrict__ csr, const int* __restrict__ rp,
        const float* __restrict__ W, const float* __restrict__ bias,
        const float* __restrict__ ln1g, const float* __restrict__ ln1b,
        const float* __restrict__ ln2g, const float* __restrict__ ln2b,
        int residual) {
    __shared__ float cat[G][2 * D];   // 8 KB; wave writes/reads only its own 2 rows
    int tid = threadIdx.x;
    int wave = tid >> 6, lane = tid & 63;
    int d0 = lane << 1;
    int n0 = blockIdx.x * G;
    int gA = wave * 2, gB = gA + 1;
    int nA = n0 + gA, nB = n0 + gB;

    float2 hA = *(const float2*)&h_in[(size_t)nA * D + d0];
    float2 hB = *(const float2*)&h_in[(size_t)nB * D + d0];
    *(float2*)&cat[gA][d0] = hA;
    *(float2*)&cat[gB][d0] = hB;

    int begA = rp[nA], endA = rp[nA + 1];
    int begB = rp[nB], endB = rp[nB + 1];
    float2 agA = gather_mean(h_in, csr, begA, endA, d0);
    float2 agB = gather_mean(h_in, csr, begB, endB, d0);
    *(float2*)&cat[gA][D + d0] = agA;
    *(float2*)&cat[gB][D + d0] = agB;
    __syncthreads();

    float2 bb = *(const float2*)&bias[d0];
    float aAx = bb.x, aAy = bb.y, aBx = bb.x, aBy = bb.y;
    #pragma unroll 8
    for (int k = 0; k < 2 * D; k += 4) {
        float4 cA = *(const float4*)&cat[gA][k];
        float4 cB = *(const float4*)&cat[gB][k];
        float2 w0 = *(const float2*)&W[(k + 0) * D + d0];
        float2 w1 = *(const float2*)&W[(k + 1) * D + d0];
        float2 w2 = *(const float2*)&W[(k + 2) * D + d0];
        float2 w3 = *(const float2*)&W[(k + 3) * D + d0];
        aAx = fmaf(cA.x, w0.x, aAx); aAy = fmaf(cA.x, w0.y, aAy);
        aAx = fmaf(cA.y, w1.x, aAx); aAy = fmaf(cA.y, w1.y, aAy);
        aAx = fmaf(cA.z, w2.x, aAx); aAy = fmaf(cA.z, w2.y, aAy);
        aAx = fmaf(cA.w, w3.x, aAx); aAy = fmaf(cA.w, w3.y, aAy);
        aBx = fmaf(cB.x, w0.x, aBx); aBy = fmaf(cB.x, w0.y, aBy);
        aBx = fmaf(cB.y, w1.x, aBx); aBy = fmaf(cB.y, w1.y, aBy);
        aBx = fmaf(cB.z, w2.x, aBx); aBy = fmaf(cB.z, w2.y, aBy);
        aBx = fmaf(cB.w, w3.x, aBx); aBy = fmaf(cB.w, w3.y, aBy);
    }

    float2 g1 = *(const float2*)&ln1g[d0];
    float2 b1 = *(const float2*)&ln1b[d0];
    float2 g2 = *(const float2*)&ln2g[d0];
    float2 b2 = *(const float2*)&ln2b[d0];
    float m, istd;

    // node A: gelu -> LN1 -> LN2 -> (gelu + residual)
    float xAx = gelu_exact(aAx), xAy = gelu_exact(aAy);
    wave_meanvar(xAx, xAy, m, istd);
    float y1x = (xAx - m) * istd * g1.x + b1.x;
    float y1y = (xAy - m) * istd * g1.y + b1.y;
    wave_meanvar(y1x, y1y, m, istd);
    float y2x = (y1x - m) * istd * g2.x + b2.x;
    float y2y = (y1y - m) * istd * g2.y + b2.y;
    float2 outA = residual ? make_float2(gelu_exact(y2x) + hA.x, gelu_exact(y2y) + hA.y)
                           : make_float2(y2x, y2y);
    *(float2*)&h_out[(size_t)nA * D + d0] = outA;

    // node B
    float xBx = gelu_exact(aBx), xBy = gelu_exact(aBy);
    wave_meanvar(xBx, xBy, m, istd);
    y1x = (xBx - m) * istd * g1.x + b1.x;
    y1y = (xBy - m) * istd * g1.y + b1.y;
    wave_meanvar(y1x, y1y, m, istd);
    y2x = (y1x - m) * istd * g2.x + b2.x;
    y2y = (y1y - m) * istd * g2.y + b2.y;
    float2 outB = residual ? make_float2(gelu_exact(y2x) + hB.x, gelu_exact(y2y) + hB.y)
                           : make_float2(y2x, y2y);
    *(float2*)&h_out[(size_t)nB * D + d0] = outB;
}

// logits[n] = tanh(h@w1 + b1) . w2 + b2
__global__ __launch_bounds__(256) void gate_v2(
        const float* __restrict__ h, const float* __restrict__ w1,
        const float* __restrict__ b1, const float* __restrict__ w2,
        const float* __restrict__ b2, float* __restrict__ logits) {
    __shared__ float hs[G][D];
    int tid = threadIdx.x;
    int wave = tid >> 6, lane = tid & 63;
    int d0 = lane << 1;
    int n0 = blockIdx.x * G;
    int gA = wave * 2, gB = gA + 1;
    int nA = n0 + gA, nB = n0 + gB;

    *(float2*)&hs[gA][d0] = *(const float2*)&h[(size_t)nA * D + d0];
    *(float2*)&hs[gB][d0] = *(const float2*)&h[(size_t)nB * D + d0];
    __syncthreads();

    float2 bb = *(const float2*)&b1[d0];
    float aAx = bb.x, aAy = bb.y, aBx = bb.x, aBy = bb.y;
    #pragma unroll 8
    for (int k = 0; k < D; k += 4) {
        float4 cA = *(const float4*)&hs[gA][k];
        float4 cB = *(const float4*)&hs[gB][k];
        float2 w0 = *(const float2*)&w1[(k + 0) * D + d0];
        float2 wv1 = *(const float2*)&w1[(k + 1) * D + d0];
        float2 wv2 = *(const float2*)&w1[(k + 2) * D + d0];
        float2 wv3 = *(const float2*)&w1[(k + 3) * D + d0];
        aAx = fmaf(cA.x, w0.x, aAx); aAy = fmaf(cA.x, w0.y, aAy);
        aAx = fmaf(cA.y, wv1.x, aAx); aAy = fmaf(cA.y, wv1.y, aAy);
        aAx = fmaf(cA.z, wv2.x, aAx); aAy = fmaf(cA.z, wv2.y, aAy);
        aAx = fmaf(cA.w, wv3.x, aAx); aAy = fmaf(cA.w, wv3.y, aAy);
        aBx = fmaf(cB.x, w0.x, aBx); aBy = fmaf(cB.x, w0.y, aBy);
        aBx = fmaf(cB.y, wv1.x, aBx); aBy = fmaf(cB.y, wv1.y, aBy);
        aBx = fmaf(cB.z, wv2.x, aBx); aBy = fmaf(cB.z, wv2.y, aBy);
        aBx = fmaf(cB.w, wv3.x, aBx); aBy = fmaf(cB.w, wv3.y, aBy);
    }
    float2 w2v = *(const float2*)&w2[d0];
    float sA = wave_sum(tanhf(aAx) * w2v.x + tanhf(aAy) * w2v.y);
    float sB = wave_sum(tanhf(aBx) * w2v.x + tanhf(aBy) * w2v.y);
    if (lane == 0) {
        float bb2 = b2[0];
        logits[nA] = sA + bb2;
        logits[nB] = sB + bb2;
    }
}

// single block: global max + sum-of-exp over N logits; also zeroes pooled (1024 elems)
__global__ void softmax_stats_kernel(const float* __restrict__ logits, float* __restrict__ stats,
                                     float* __restrict__ pooled) {
    __shared__ float sbuf[16];
    int tid = threadIdx.x;
    pooled[tid] = 0.f;  // blockDim == 1024 == B_GRAPHS * D
    float mx = -INFINITY;
    for (int i = tid; i < N_NODES; i += 1024) mx = fmaxf(mx, logits[i]);
    #pragma unroll
    for (int o = 32; o >= 1; o >>= 1) mx = fmaxf(mx, __shfl_down(mx, o));
    if ((tid & 63) == 0) sbuf[tid >> 6] = mx;
    __syncthreads();
    if (tid == 0) {
        float m = sbuf[0];
        for (int w = 1; w < 16; ++w) m = fmaxf(m, sbuf[w]);
        sbuf[0] = m;
    }
    __syncthreads();
    mx = sbuf[0];
    __syncthreads();
    float sum = 0.f;
    for (int i = tid; i < N_NODES; i += 1024) sum += expf(logits[i] - mx);
    #pragma unroll
    for (int o = 32; o >= 1; o >>= 1) sum += __shfl_down(sum, o);
    if ((tid & 63) == 0) sbuf[tid >> 6] = sum;
    __syncthreads();
    if (tid == 0) {
        float s = 0.f;
        for (int w = 0; w < 16; ++w) s += sbuf[w];
        stats[0] = mx;
        stats[1] = 1.0f / s;
    }
}

// gate[n] = exp(logit-max)*invsum; pooled[batch] += h*gate (batch sorted -> run-flush)
#define POOL_CHUNK 128
__global__ void gate_pool_kernel(const float* __restrict__ h, const float* __restrict__ logits,
                                 const float* __restrict__ stats, const int* __restrict__ batch,
                                 float* __restrict__ gate_out, float* __restrict__ pooled) {
    __shared__ float gs[POOL_CHUNK];
    __shared__ int bs[POOL_CHUNK];
    int n0 = blockIdx.x * POOL_CHUNK;
    int d = threadIdx.x;
    float mx = stats[0], inv = stats[1];
    int nj = n0 + d;
    if (nj < N_NODES) {
        float gv = expf(logits[nj] - mx) * inv;
        gs[d] = gv;
        bs[d] = batch[nj];
        gate_out[nj] = gv;
    }
    __syncthreads();
    int count = min(POOL_CHUNK, N_NODES - n0);
    float acc = 0.f;
    int cur = bs[0];
    for (int t = 0; t < count; ++t) {
        int bn = bs[t];
        if (bn != cur) { atomicAdd(&pooled[cur * D + d], acc); acc = 0.f; cur = bn; }
        acc += h[(size_t)(n0 + t) * D + d] * gs[t];
    }
    atomicAdd(&pooled[cur * D + d], acc);
}

__global__ void out_proj_kernel(const float* __restrict__ pooled, const float* __restrict__ w,
                                const float* __restrict__ b, const float* __restrict__ g,
                                const float* __restrict__ beta, float* __restrict__ emb) {
    __shared__ float ps[D];
    __shared__ float sbuf[2];
    int bg = blockIdx.x, d = threadIdx.x;
    ps[d] = pooled[bg * D + d];
    __syncthreads();
    float acc = b[d];
    #pragma unroll 8
    for (int k = 0; k < D; ++k) acc += ps[k] * w[k * D + d];
    float s = acc, q = acc * acc;
    #pragma unroll
    for (int o = 32; o >= 1; o >>= 1) { s += __shfl_down(s, o); q += __shfl_down(q, o); }
    if ((d & 63) == 0) { sbuf[d >> 6] = s; }
    __syncthreads();
    float fullsum = sbuf[0] + sbuf[1];
    __syncthreads();
    if ((d & 63) == 0) { sbuf[d >> 6] = q; }
    __syncthreads();
    float fullsq = sbuf[0] + sbuf[1];
    float m = fullsum * (1.0f / D);
    float var = fullsq * (1.0f / D) - m * m;
    float y = (acc - m) * rsqrtf(var + 1e-5f) * g[d] + beta[d];
    emb[bg * D + d] = gelu_exact(y);
}

extern "C" void kernel_launch(void* const* d_in, const int* in_sizes, int n_in,
                              void* d_out, int out_size, void* d_ws, size_t ws_size,
                              hipStream_t stream) {
    const float* x        = (const float*)d_in[0];
    const int*   edge     = (const int*)d_in[1];
    const int*   batch    = (const int*)d_in[2];
    const float* w_in     = (const float*)d_in[3];
    const float* b_in     = (const float*)d_in[4];
    const float* ln_in_g  = (const float*)d_in[5];
    const float* ln_in_b  = (const float*)d_in[6];
    const float* gnn_w    = (const float*)d_in[7];
    const float* gnn_b    = (const float*)d_in[8];
    const float* gnn_ln_g = (const float*)d_in[9];
    const float* gnn_ln_b = (const float*)d_in[10];
    const float* norm_g   = (const float*)d_in[11];
    const float* norm_b   = (const float*)d_in[12];
    const float* gate_w1  = (const float*)d_in[13];
    const float* gate_b1  = (const float*)d_in[14];
    const float* gate_w2  = (const float*)d_in[15];
    const float* gate_b2  = (const float*)d_in[16];
    const float* out_w    = (const float*)d_in[17];
    const float* out_b    = (const float*)d_in[18];
    const float* out_ln_g = (const float*)d_in[19];
    const float* out_ln_b = (const float*)d_in[20];

    const int* src = edge;             // edge_index[0]
    const int* dst = edge + N_EDGES;   // edge_index[1]

    float* out      = (float*)d_out;
    float* emb      = out;                               // (8,128)
    float* hA       = out + B_GRAPHS * D;                // (N,128) final h location
    float* gate_out = hA + (size_t)N_NODES * D;          // (N,)

    // workspace: hB first (N*D floats); CSR-build temporaries deg/cursor OVERLAID in hB
    // (they die before input_proj writes hB; stream order guarantees safety)
    float* hB       = (float*)d_ws;                      // N*D floats
    int*   deg_i    = (int*)d_ws;                        // N      (overlay)
    int*   cursor   = (int*)d_ws + N_NODES;              // N+1    (overlay)
    int*   row_ptr  = (int*)(hB + (size_t)N_NODES * D);  // N+1
    int*   csr      = row_ptr + N_NODES + 1;             // E
    float* logits   = (float*)(csr + N_EDGES);           // N
    float* pooled   = logits + N_NODES;                  // 1024
    float* stats    = pooled + B_GRAPHS * D;             // 2
    int*   partials = (int*)(stats + 2);                 // NPART

    // CSR build
    zero_int_kernel<<<128, 256, 0, stream>>>(deg_i, N_NODES);
    degree_kernel<<<(N_EDGES + 255) / 256, 256, 0, stream>>>(dst, deg_i);
    scan_partials_kernel<<<NPART, SCAN_B, 0, stream>>>(deg_i, partials);
    scan_offsets_kernel<<<1, 128, 0, stream>>>(partials, row_ptr);
    scan_apply_kernel<<<NPART, SCAN_B, 0, stream>>>(deg_i, partials, row_ptr, cursor);
    fill_kernel<<<(N_EDGES + 255) / 256, 256, 0, stream>>>(src, dst, cursor, csr);

    // input proj -> hB
    input_proj_v2<<<N_NODES / G, 256, 0, stream>>>(x, w_in, b_in, ln_in_g, ln_in_b, hB);

    // ping-pong: hB -> hA -> hB -> hA  (final h lands in hA = d_out slice)
    const float* hin[3]  = {hB, hA, hB};
    float*       hout[3] = {hA, hB, hA};
    for (int i = 0; i < NLAYER; ++i) {
        gnn_layer_v2<<<N_NODES / G, 256, 0, stream>>>(
            hin[i], hout[i], csr, row_ptr,
            gnn_w + (size_t)i * 2 * D * D, gnn_b + i * D,
            gnn_ln_g + i * D, gnn_ln_b + i * D,
            norm_g + i * D, norm_b + i * D,
            (i < NLAYER - 1) ? 1 : 0);
    }

    gate_v2<<<N_NODES / G, 256, 0, stream>>>(hA, gate_w1, gate_b1, gate_w2, gate_b2, logits);
    softmax_stats_kernel<<<1, 1024, 0, stream>>>(logits, stats, pooled);
    gate_pool_kernel<<<(N_NODES + POOL_CHUNK - 1) / POOL_CHUNK, POOL_CHUNK, 0, stream>>>(
        hA, logits, stats, batch, gate_out, pooled);
    out_proj_kernel<<<B_GRAPHS, D, 0, stream>>>(pooled, out_w, out_b, out_ln_g, out_ln_b, emb);
}

// Round 5
// 795.244 us; speedup vs baseline: 1.3385x; 1.3385x over previous
//
#include <hip/hip_runtime.h>
#include <math.h>

#define N_NODES 50000
#define N_EDGES 800000
#define F_IN 64
#define D 128
#define NLAYER 3
#define B_GRAPHS 8
#define GB 32               // nodes per block (4 waves x 8 nodes)
#define NPW 8               // nodes per wave
#define NBLK ((N_NODES + GB - 1) / GB)            // 1563 (last block partial)
#define SCAN_B 512
#define NPART ((N_NODES + SCAN_B - 1) / SCAN_B)   // 98

__device__ __forceinline__ float gelu_exact(float x) {
    return 0.5f * x * (1.0f + erff(x * 0.7071067811865476f));
}

__device__ __forceinline__ float wave_sum(float v) {
    #pragma unroll
    for (int o = 32; o >= 1; o >>= 1) v += __shfl_xor(v, o);
    return v;
}

// mean / inv-std over a 128-wide row held as float2 per lane (one wave)
__device__ __forceinline__ void wave_meanvar(float vx, float vy, float& mean, float& inv_std) {
    float s = vx + vy;
    float q = vx * vx + vy * vy;
    #pragma unroll
    for (int o = 32; o >= 1; o >>= 1) { s += __shfl_xor(s, o); q += __shfl_xor(q, o); }
    mean = s * (1.0f / D);
    float var = q * (1.0f / D) - mean * mean;
    inv_std = rsqrtf(var + 1e-5f);
}

// ---------------- CSR build ----------------

__global__ void zero_int_kernel(int* __restrict__ p, int n) {
    int i = blockIdx.x * blockDim.x + threadIdx.x;
    int stride = gridDim.x * blockDim.x;
    for (; i < n; i += stride) p[i] = 0;
}

__global__ void degree_kernel(const int* __restrict__ dst, int* __restrict__ deg) {
    int e = blockIdx.x * blockDim.x + threadIdx.x;
    if (e < N_EDGES) atomicAdd(&deg[dst[e]], 1);
}

__global__ __launch_bounds__(SCAN_B) void scan_partials_kernel(const int* __restrict__ deg,
                                                               int* __restrict__ partials) {
    __shared__ int wsum[8];
    int tid = threadIdx.x;
    int lane = tid & 63, wave = tid >> 6;
    int i = blockIdx.x * SCAN_B + tid;
    int v = (i < N_NODES) ? deg[i] : 0;
    #pragma unroll
    for (int o = 32; o >= 1; o >>= 1) v += __shfl_xor(v, o);
    if (lane == 0) wsum[wave] = v;
    __syncthreads();
    if (tid == 0) {
        int t = 0;
        #pragma unroll
        for (int w = 0; w < 8; ++w) t += wsum[w];
        partials[blockIdx.x] = t;
    }
}

__global__ void scan_offsets_kernel(int* __restrict__ partials, int* __restrict__ row_ptr) {
    __shared__ int wtot[2];
    int tid = threadIdx.x;          // 128 threads, 2 waves
    int lane = tid & 63, wave = tid >> 6;
    int v = (tid < NPART) ? partials[tid] : 0;
    int x = v;
    #pragma unroll
    for (int o = 1; o < 64; o <<= 1) { int nb = __shfl_up(x, o); if (lane >= o) x += nb; }
    if (lane == 63) wtot[wave] = x;
    __syncthreads();
    if (wave == 1) x += wtot[0];
    if (tid < NPART) partials[tid] = x - v;       // exclusive
    if (tid == 127) row_ptr[N_NODES] = x;         // grand total
}

__global__ __launch_bounds__(SCAN_B) void scan_apply_kernel(const int* __restrict__ deg,
        const int* __restrict__ partials, int* __restrict__ row_ptr, int* __restrict__ cursor) {
    __shared__ int wsum[8];
    int tid = threadIdx.x;
    int lane = tid & 63, wave = tid >> 6;
    int i = blockIdx.x * SCAN_B + tid;
    int v = (i < N_NODES) ? deg[i] : 0;
    int x = v;
    #pragma unroll
    for (int o = 1; o < 64; o <<= 1) { int nb = __shfl_up(x, o); if (lane >= o) x += nb; }
    if (lane == 63) wsum[wave] = x;
    __syncthreads();
    int waveoff = 0;
    #pragma unroll
    for (int w = 0; w < 8; ++w) waveoff += (w < wave) ? wsum[w] : 0;
    int excl = partials[blockIdx.x] + waveoff + x - v;
    if (i < N_NODES) { row_ptr[i] = excl; cursor[i] = excl; }
}

__global__ void fill_kernel(const int* __restrict__ src, const int* __restrict__ dst,
                            int* __restrict__ cursor, int* __restrict__ csr) {
    int e = blockIdx.x * blockDim.x + threadIdx.x;
    if (e < N_EDGES) {
        int t = dst[e];
        int pos = atomicAdd(&cursor[t], 1);
        csr[pos] = src[e];
    }
}

// ---------------- node kernels: wave = 8 nodes, lane = 2 dims ----------------

// mean-neighbor gather for one node, 2 dims per lane, 4-way unrolled for ILP
__device__ __forceinline__ float2 gather_mean(const float* __restrict__ h_in,
                                              const int* __restrict__ csr,
                                              int beg, int end, int d0) {
    float ax0 = 0.f, ay0 = 0.f, ax1 = 0.f, ay1 = 0.f;
    float ax2 = 0.f, ay2 = 0.f, ax3 = 0.f, ay3 = 0.f;
    int e = beg;
    for (; e + 3 < end; e += 4) {
        int s0 = csr[e], s1 = csr[e + 1], s2 = csr[e + 2], s3 = csr[e + 3];
        float2 v0 = *(const float2*)&h_in[(size_t)s0 * D + d0];
        float2 v1 = *(const float2*)&h_in[(size_t)s1 * D + d0];
        float2 v2 = *(const float2*)&h_in[(size_t)s2 * D + d0];
        float2 v3 = *(const float2*)&h_in[(size_t)s3 * D + d0];
        ax0 += v0.x; ay0 += v0.y;
        ax1 += v1.x; ay1 += v1.y;
        ax2 += v2.x; ay2 += v2.y;
        ax3 += v3.x; ay3 += v3.y;
    }
    for (; e < end; ++e) {
        float2 v = *(const float2*)&h_in[(size_t)csr[e] * D + d0];
        ax0 += v.x; ay0 += v.y;
    }
    float inv = 1.0f / fmaxf((float)(end - beg), 1.0f);
    return make_float2((ax0 + ax1 + ax2 + ax3) * inv, (ay0 + ay1 + ay2 + ay3) * inv);
}

// h = gelu(ln(x @ w_in + b_in)); 32 nodes/block, 8 per wave
__global__ __launch_bounds__(256) void input_proj_v3(
        const float* __restrict__ x, const float* __restrict__ w,
        const float* __restrict__ b, const float* __restrict__ gam,
        const float* __restrict__ bet, float* __restrict__ h) {
    __shared__ float xs[GB][F_IN];   // 8 KB; wave-private rows
    int tid = threadIdx.x;
    int wave = tid >> 6, lane = tid & 63;
    int d0 = lane << 1;
    int gbase = wave * NPW;
    int n0 = blockIdx.x * GB + gbase;

    #pragma unroll
    for (int j = 0; j < NPW; ++j) {
        int n = n0 + j;
        int ns = (n < N_NODES) ? n : (N_NODES - 1);
        xs[gbase + j][lane] = x[(size_t)ns * F_IN + lane];
    }

    float2 bb = *(const float2*)&b[d0];
    float ax[NPW], ay[NPW];
    #pragma unroll
    for (int j = 0; j < NPW; ++j) { ax[j] = bb.x; ay[j] = bb.y; }

    #pragma unroll 4
    for (int k = 0; k < F_IN; k += 4) {
        float2 w0 = *(const float2*)&w[(k + 0) * D + d0];
        float2 w1 = *(const float2*)&w[(k + 1) * D + d0];
        float2 w2 = *(const float2*)&w[(k + 2) * D + d0];
        float2 w3 = *(const float2*)&w[(k + 3) * D + d0];
        #pragma unroll
        for (int j = 0; j < NPW; ++j) {
            float4 a = *(const float4*)&xs[gbase + j][k];
            ax[j] = fmaf(a.x, w0.x, ax[j]); ay[j] = fmaf(a.x, w0.y, ay[j]);
            ax[j] = fmaf(a.y, w1.x, ax[j]); ay[j] = fmaf(a.y, w1.y, ay[j]);
            ax[j] = fmaf(a.z, w2.x, ax[j]); ay[j] = fmaf(a.z, w2.y, ay[j]);
            ax[j] = fmaf(a.w, w3.x, ax[j]); ay[j] = fmaf(a.w, w3.y, ay[j]);
        }
    }
    float2 gg = *(const float2*)&gam[d0];
    float2 bt = *(const float2*)&bet[d0];
    #pragma unroll
    for (int j = 0; j < NPW; ++j) {
        float m, istd;
        wave_meanvar(ax[j], ay[j], m, istd);
        int n = n0 + j;
        if (n < N_NODES) {
            float2 o = make_float2(gelu_exact((ax[j] - m) * istd * gg.x + bt.x),
                                   gelu_exact((ay[j] - m) * istd * gg.y + bt.y));
            *(float2*)&h[(size_t)n * D + d0] = o;
        }
    }
}

// fused: CSR mean-gather + [h,agg]@W + gelu + LN1 + LN2 (+gelu+residual); ping-pong
// 32 nodes/block, 8 per wave; LDS rows wave-private -> NO __syncthreads.
__global__ __launch_bounds__(256) void gnn_layer_v3(
        const float* __restrict__ h_in, float* __restrict__ h_out,
        const int* __restrict__ csr, const int* __restrict__ rp,
        const float* __restrict__ W, const float* __restrict__ bias,
        const float* __restrict__ ln1g, const float* __restrict__ ln1b,
        const float* __restrict__ ln2g, const float* __restrict__ ln2b,
        int residual) {
    __shared__ float cat[GB][2 * D];   // 32 KB
    int tid = threadIdx.x;
    int wave = tid >> 6, lane = tid & 63;
    int d0 = lane << 1;
    int gbase = wave * NPW;
    int n0 = blockIdx.x * GB + gbase;

    float2 hres[NPW];
    #pragma unroll
    for (int j = 0; j < NPW; ++j) {
        int n = n0 + j;
        int ns = (n < N_NODES) ? n : (N_NODES - 1);
        float2 hv = *(const float2*)&h_in[(size_t)ns * D + d0];
        hres[j] = hv;
        *(float2*)&cat[gbase + j][d0] = hv;
        int beg = rp[ns], end = rp[ns + 1];
        float2 ag = gather_mean(h_in, csr, beg, end, d0);
        *(float2*)&cat[gbase + j][D + d0] = ag;
    }
    // wave-private LDS rows: compiler inserts lgkmcnt waits; no barrier needed.

    float2 bb = *(const float2*)&bias[d0];
    float ax[NPW], ay[NPW];
    #pragma unroll
    for (int j = 0; j < NPW; ++j) { ax[j] = bb.x; ay[j] = bb.y; }

    #pragma unroll 4
    for (int k = 0; k < 2 * D; k += 4) {
        float2 w0 = *(const float2*)&W[(k + 0) * D + d0];
        float2 w1 = *(const float2*)&W[(k + 1) * D + d0];
        float2 w2 = *(const float2*)&W[(k + 2) * D + d0];
        float2 w3 = *(const float2*)&W[(k + 3) * D + d0];
        #pragma unroll
        for (int j = 0; j < NPW; ++j) {
            float4 a = *(const float4*)&cat[gbase + j][k];
            ax[j] = fmaf(a.x, w0.x, ax[j]); ay[j] = fmaf(a.x, w0.y, ay[j]);
            ax[j] = fmaf(a.y, w1.x, ax[j]); ay[j] = fmaf(a.y, w1.y, ay[j]);
            ax[j] = fmaf(a.z, w2.x, ax[j]); ay[j] = fmaf(a.z, w2.y, ay[j]);
            ax[j] = fmaf(a.w, w3.x, ax[j]); ay[j] = fmaf(a.w, w3.y, ay[j]);
        }
    }

    float2 g1 = *(const float2*)&ln1g[d0];
    float2 b1 = *(const float2*)&ln1b[d0];
    float2 g2 = *(const float2*)&ln2g[d0];
    float2 b2 = *(const float2*)&ln2b[d0];
    #pragma unroll
    for (int j = 0; j < NPW; ++j) {
        float m, istd;
        float xx = gelu_exact(ax[j]), xy = gelu_exact(ay[j]);
        wave_meanvar(xx, xy, m, istd);
        float y1x = (xx - m) * istd * g1.x + b1.x;
        float y1y = (xy - m) * istd * g1.y + b1.y;
        wave_meanvar(y1x, y1y, m, istd);
        float y2x = (y1x - m) * istd * g2.x + b2.x;
        float y2y = (y1y - m) * istd * g2.y + b2.y;
        float2 o = residual ? make_float2(gelu_exact(y2x) + hres[j].x, gelu_exact(y2y) + hres[j].y)
                            : make_float2(y2x, y2y);
        int n = n0 + j;
        if (n < N_NODES) *(float2*)&h_out[(size_t)n * D + d0] = o;
    }
}

// logits[n] = tanh(h@w1 + b1) . w2 + b2; 32 nodes/block, 8 per wave
__global__ __launch_bounds__(256) void gate_v3(
        const float* __restrict__ h, const float* __restrict__ w1,
        const float* __restrict__ b1, const float* __restrict__ w2,
        const float* __restrict__ b2, float* __restrict__ logits) {
    __shared__ float hs[GB][D];   // 16 KB; wave-private rows
    int tid = threadIdx.x;
    int wave = tid >> 6, lane = tid & 63;
    int d0 = lane << 1;
    int gbase = wave * NPW;
    int n0 = blockIdx.x * GB + gbase;

    #pragma unroll
    for (int j = 0; j < NPW; ++j) {
        int n = n0 + j;
        int ns = (n < N_NODES) ? n : (N_NODES - 1);
        *(float2*)&hs[gbase + j][d0] = *(const float2*)&h[(size_t)ns * D + d0];
    }

    float2 bb = *(const float2*)&b1[d0];
    float ax[NPW], ay[NPW];
    #pragma unroll
    for (int j = 0; j < NPW; ++j) { ax[j] = bb.x; ay[j] = bb.y; }

    #pragma unroll 4
    for (int k = 0; k < D; k += 4) {
        float2 w0 = *(const float2*)&w1[(k + 0) * D + d0];
        float2 wv1 = *(const float2*)&w1[(k + 1) * D + d0];
        float2 wv2 = *(const float2*)&w1[(k + 2) * D + d0];
        float2 wv3 = *(const float2*)&w1[(k + 3) * D + d0];
        #pragma unroll
        for (int j = 0; j < NPW; ++j) {
            float4 a = *(const float4*)&hs[gbase + j][k];
            ax[j] = fmaf(a.x, w0.x, ax[j]); ay[j] = fmaf(a.x, w0.y, ay[j]);
            ax[j] = fmaf(a.y, wv1.x, ax[j]); ay[j] = fmaf(a.y, wv1.y, ay[j]);
            ax[j] = fmaf(a.z, wv2.x, ax[j]); ay[j] = fmaf(a.z, wv2.y, ay[j]);
            ax[j] = fmaf(a.w, wv3.x, ax[j]); ay[j] = fmaf(a.w, wv3.y, ay[j]);
        }
    }
    float2 w2v = *(const float2*)&w2[d0];
    float bb2 = b2[0];
    #pragma unroll
    for (int j = 0; j < NPW; ++j) {
        float s = wave_sum(tanhf(ax[j]) * w2v.x + tanhf(ay[j]) * w2v.y);
        int n = n0 + j;
        if (lane == 0 && n < N_NODES) logits[n] = s + bb2;
    }
}

// single block: global max + sum-of-exp over N logits; also zeroes pooled (1024 elems)
__global__ void softmax_stats_kernel(const float* __restrict__ logits, float* __restrict__ stats,
                                     float* __restrict__ pooled) {
    __shared__ float sbuf[16];
    int tid = threadIdx.x;
    pooled[tid] = 0.f;  // blockDim == 1024 == B_GRAPHS * D
    float mx = -INFINITY;
    for (int i = tid; i < N_NODES; i += 1024) mx = fmaxf(mx, logits[i]);
    #pragma unroll
    for (int o = 32; o >= 1; o >>= 1) mx = fmaxf(mx, __shfl_down(mx, o));
    if ((tid & 63) == 0) sbuf[tid >> 6] = mx;
    __syncthreads();
    if (tid == 0) {
        float m = sbuf[0];
        for (int w = 1; w < 16; ++w) m = fmaxf(m, sbuf[w]);
        sbuf[0] = m;
    }
    __syncthreads();
    mx = sbuf[0];
    __syncthreads();
    float sum = 0.f;
    for (int i = tid; i < N_NODES; i += 1024) sum += expf(logits[i] - mx);
    #pragma unroll
    for (int o = 32; o >= 1; o >>= 1) sum += __shfl_down(sum, o);
    if ((tid & 63) == 0) sbuf[tid >> 6] = sum;
    __syncthreads();
    if (tid == 0) {
        float s = 0.f;
        for (int w = 0; w < 16; ++w) s += sbuf[w];
        stats[0] = mx;
        stats[1] = 1.0f / s;
    }
}

// gate[n] = exp(logit-max)*invsum; pooled[batch] += h*gate (batch sorted -> run-flush)
#define POOL_CHUNK 128
__global__ void gate_pool_kernel(const float* __restrict__ h, const float* __restrict__ logits,
                                 const float* __restrict__ stats, const int* __restrict__ batch,
                                 float* __restrict__ gate_out, float* __restrict__ pooled) {
    __shared__ float gs[POOL_CHUNK];
    __shared__ int bs[POOL_CHUNK];
    int n0 = blockIdx.x * POOL_CHUNK;
    int d = threadIdx.x;
    float mx = stats[0], inv = stats[1];
    int nj = n0 + d;
    if (nj < N_NODES) {
        float gv = expf(logits[nj] - mx) * inv;
        gs[d] = gv;
        bs[d] = batch[nj];
        gate_out[nj] = gv;
    }
    __syncthreads();
    int count = min(POOL_CHUNK, N_NODES - n0);
    float acc = 0.f;
    int cur = bs[0];
    for (int t = 0; t < count; ++t) {
        int bn = bs[t];
        if (bn != cur) { atomicAdd(&pooled[cur * D + d], acc); acc = 0.f; cur = bn; }
        acc += h[(size_t)(n0 + t) * D + d] * gs[t];
    }
    atomicAdd(&pooled[cur * D + d], acc);
}

__global__ void out_proj_kernel(const float* __restrict__ pooled, const float* __restrict__ w,
                                const float* __restrict__ b, const float* __restrict__ g,
                                const float* __restrict__ beta, float* __restrict__ emb) {
    __shared__ float ps[D];
    __shared__ float sbuf[2];
    int bg = blockIdx.x, d = threadIdx.x;
    ps[d] = pooled[bg * D + d];
    __syncthreads();
    float acc = b[d];
    #pragma unroll 8
    for (int k = 0; k < D; ++k) acc += ps[k] * w[k * D + d];
    float s = acc, q = acc * acc;
    #pragma unroll
    for (int o = 32; o >= 1; o >>= 1) { s += __shfl_down(s, o); q += __shfl_down(q, o); }
    if ((d & 63) == 0) { sbuf[d >> 6] = s; }
    __syncthreads();
    float fullsum = sbuf[0] + sbuf[1];
    __syncthreads();
    if ((d & 63) == 0) { sbuf[d >> 6] = q; }
    __syncthreads();
    float fullsq = sbuf[0] + sbuf[1];
    float m = fullsum * (1.0f / D);
    float var = fullsq * (1.0f / D) - m * m;
    float y = (acc - m) * rsqrtf(var + 1e-5f) * g[d] + beta[d];
    emb[bg * D + d] = gelu_exact(y);
}

extern "C" void kernel_launch(void* const* d_in, const int* in_sizes, int n_in,
                              void* d_out, int out_size, void* d_ws, size_t ws_size,
                              hipStream_t stream) {
    const float* x        = (const float*)d_in[0];
    const int*   edge     = (const int*)d_in[1];
    const int*   batch    = (const int*)d_in[2];
    const float* w_in     = (const float*)d_in[3];
    const float* b_in     = (const float*)d_in[4];
    const float* ln_in_g  = (const float*)d_in[5];
    const float* ln_in_b  = (const float*)d_in[6];
    const float* gnn_w    = (const float*)d_in[7];
    const float* gnn_b    = (const float*)d_in[8];
    const float* gnn_ln_g = (const float*)d_in[9];
    const float* gnn_ln_b = (const float*)d_in[10];
    const float* norm_g   = (const float*)d_in[11];
    const float* norm_b   = (const float*)d_in[12];
    const float* gate_w1  = (const float*)d_in[13];
    const float* gate_b1  = (const float*)d_in[14];
    const float* gate_w2  = (const float*)d_in[15];
    const float* gate_b2  = (const float*)d_in[16];
    const float* out_w    = (const float*)d_in[17];
    const float* out_b    = (const float*)d_in[18];
    const float* out_ln_g = (const float*)d_in[19];
    const float* out_ln_b = (const float*)d_in[20];

    const int* src = edge;             // edge_index[0]
    const int* dst = edge + N_EDGES;   // edge_index[1]

    float* out      = (float*)d_out;
    float* emb      = out;                               // (8,128)
    float* hA       = out + B_GRAPHS * D;                // (N,128) final h location
    float* gate_out = hA + (size_t)N_NODES * D;          // (N,)

    // workspace: hB first (N*D floats); CSR-build temporaries deg/cursor OVERLAID in hB
    float* hB       = (float*)d_ws;                      // N*D floats
    int*   deg_i    = (int*)d_ws;                        // N      (overlay)
    int*   cursor   = (int*)d_ws + N_NODES;              // N+1    (overlay)
    int*   row_ptr  = (int*)(hB + (size_t)N_NODES * D);  // N+1
    int*   csr      = row_ptr + N_NODES + 1;             // E
    float* logits   = (float*)(csr + N_EDGES);           // N
    float* pooled   = logits + N_NODES;                  // 1024
    float* stats    = pooled + B_GRAPHS * D;             // 2
    int*   partials = (int*)(stats + 2);                 // NPART

    // CSR build
    zero_int_kernel<<<128, 256, 0, stream>>>(deg_i, N_NODES);
    degree_kernel<<<(N_EDGES + 255) / 256, 256, 0, stream>>>(dst, deg_i);
    scan_partials_kernel<<<NPART, SCAN_B, 0, stream>>>(deg_i, partials);
    scan_offsets_kernel<<<1, 128, 0, stream>>>(partials, row_ptr);
    scan_apply_kernel<<<NPART, SCAN_B, 0, stream>>>(deg_i, partials, row_ptr, cursor);
    fill_kernel<<<(N_EDGES + 255) / 256, 256, 0, stream>>>(src, dst, cursor, csr);

    // input proj -> hB
    input_proj_v3<<<NBLK, 256, 0, stream>>>(x, w_in, b_in, ln_in_g, ln_in_b, hB);

    // ping-pong: hB -> hA -> hB -> hA  (final h lands in hA = d_out slice)
    const float* hin[3]  = {hB, hA, hB};
    float*       hout[3] = {hA, hB, hA};
    for (int i = 0; i < NLAYER; ++i) {
        gnn_layer_v3<<<NBLK, 256, 0, stream>>>(
            hin[i], hout[i], csr, row_ptr,
            gnn_w + (size_t)i * 2 * D * D, gnn_b + i * D,
            gnn_ln_g + i * D, gnn_ln_b + i * D,
            norm_g + i * D, norm_b + i * D,
            (i < NLAYER - 1) ? 1 : 0);
    }

    gate_v3<<<NBLK, 256, 0, stream>>>(hA, gate_w1, gate_b1, gate_w2, gate_b2, logits);
    softmax_stats_kernel<<<1, 1024, 0, stream>>>(logits, stats, pooled);
    gate_pool_kernel<<<(N_NODES + POOL_CHUNK - 1) / POOL_CHUNK, POOL_CHUNK, 0, stream>>>(
        hA, logits, stats, batch, gate_out, pooled);
    out_proj_kernel<<<B_GRAPHS, D, 0, stream>>>(pooled, out_w, out_b, out_ln_g, out_ln_b, emb);
}

// Round 6
// 703.136 us; speedup vs baseline: 1.5138x; 1.1310x over previous
//
#include <hip/hip_runtime.h>
#include <math.h>

#define N_NODES 50000
#define N_EDGES 800000
#define F_IN 64
#define D 128
#define NLAYER 3
#define B_GRAPHS 8
#define GB 32               // nodes per block (4 waves x 8 nodes staged; MFMA tiles 2x2)
#define NPW 8               // nodes per wave (staging)
#define NBLK ((N_NODES + GB - 1) / GB)            // 1563 (last block partial)
#define SCAN_B 512
#define NPART ((N_NODES + SCAN_B - 1) / SCAN_B)   // 98
#define CATP 264            // cat row stride in ushorts (256 + 8 pad)

typedef float f32x4 __attribute__((ext_vector_type(4)));
typedef short bf16x8 __attribute__((ext_vector_type(8)));

__device__ __forceinline__ float gelu_exact(float x) {
    return 0.5f * x * (1.0f + erff(x * 0.7071067811865476f));
}

__device__ __forceinline__ float wave_sum(float v) {
    #pragma unroll
    for (int o = 32; o >= 1; o >>= 1) v += __shfl_xor(v, o);
    return v;
}

__device__ __forceinline__ void wave_meanvar(float vx, float vy, float& mean, float& inv_std) {
    float s = vx + vy;
    float q = vx * vx + vy * vy;
    #pragma unroll
    for (int o = 32; o >= 1; o >>= 1) { s += __shfl_xor(s, o); q += __shfl_xor(q, o); }
    mean = s * (1.0f / D);
    float var = q * (1.0f / D) - mean * mean;
    inv_std = rsqrtf(var + 1e-5f);
}

// fp32 -> bf16 round-to-nearest-even
__device__ __forceinline__ unsigned short f2bf(float f) {
    unsigned int u = __float_as_uint(f);
    u = (u + 0x7fffu + ((u >> 16) & 1u)) >> 16;
    return (unsigned short)u;
}
__device__ __forceinline__ unsigned int pack2bf(float a, float b) {
    return (unsigned int)f2bf(a) | ((unsigned int)f2bf(b) << 16);
}

// ---------------- CSR build ----------------

__global__ void zero_int_kernel(int* __restrict__ p, int n) {
    int i = blockIdx.x * blockDim.x + threadIdx.x;
    int stride = gridDim.x * blockDim.x;
    for (; i < n; i += stride) p[i] = 0;
}

__global__ void degree_kernel(const int* __restrict__ dst, int* __restrict__ deg) {
    int e = blockIdx.x * blockDim.x + threadIdx.x;
    if (e < N_EDGES) atomicAdd(&deg[dst[e]], 1);
}

__global__ __launch_bounds__(SCAN_B) void scan_partials_kernel(const int* __restrict__ deg,
                                                               int* __restrict__ partials) {
    __shared__ int wsum[8];
    int tid = threadIdx.x;
    int lane = tid & 63, wave = tid >> 6;
    int i = blockIdx.x * SCAN_B + tid;
    int v = (i < N_NODES) ? deg[i] : 0;
    #pragma unroll
    for (int o = 32; o >= 1; o >>= 1) v += __shfl_xor(v, o);
    if (lane == 0) wsum[wave] = v;
    __syncthreads();
    if (tid == 0) {
        int t = 0;
        #pragma unroll
        for (int w = 0; w < 8; ++w) t += wsum[w];
        partials[blockIdx.x] = t;
    }
}

__global__ void scan_offsets_kernel(int* __restrict__ partials, int* __restrict__ row_ptr) {
    __shared__ int wtot[2];
    int tid = threadIdx.x;          // 128 threads, 2 waves
    int lane = tid & 63, wave = tid >> 6;
    int v = (tid < NPART) ? partials[tid] : 0;
    int x = v;
    #pragma unroll
    for (int o = 1; o < 64; o <<= 1) { int nb = __shfl_up(x, o); if (lane >= o) x += nb; }
    if (lane == 63) wtot[wave] = x;
    __syncthreads();
    if (wave == 1) x += wtot[0];
    if (tid < NPART) partials[tid] = x - v;       // exclusive
    if (tid == 127) row_ptr[N_NODES] = x;         // grand total
}

__global__ __launch_bounds__(SCAN_B) void scan_apply_kernel(const int* __restrict__ deg,
        const int* __restrict__ partials, int* __restrict__ row_ptr, int* __restrict__ cursor) {
    __shared__ int wsum[8];
    int tid = threadIdx.x;
    int lane = tid & 63, wave = tid >> 6;
    int i = blockIdx.x * SCAN_B + tid;
    int v = (i < N_NODES) ? deg[i] : 0;
    int x = v;
    #pragma unroll
    for (int o = 1; o < 64; o <<= 1) { int nb = __shfl_up(x, o); if (lane >= o) x += nb; }
    if (lane == 63) wsum[wave] = x;
    __syncthreads();
    int waveoff = 0;
    #pragma unroll
    for (int w = 0; w < 8; ++w) waveoff += (w < wave) ? wsum[w] : 0;
    int excl = partials[blockIdx.x] + waveoff + x - v;
    if (i < N_NODES) { row_ptr[i] = excl; cursor[i] = excl; }
}

__global__ void fill_kernel(const int* __restrict__ src, const int* __restrict__ dst,
                            int* __restrict__ cursor, int* __restrict__ csr) {
    int e = blockIdx.x * blockDim.x + threadIdx.x;
    if (e < N_EDGES) {
        int t = dst[e];
        int pos = atomicAdd(&cursor[t], 1);
        csr[pos] = src[e];
    }
}

// W prep: gnn_w fp32 [L][2D][D] -> wt bf16 [L][n=D][k=2D]  (B-fragment friendly)
__global__ void wprep_kernel(const float* __restrict__ gnn_w, unsigned short* __restrict__ wt) {
    int idx = blockIdx.x * 256 + threadIdx.x;
    if (idx >= NLAYER * D * 2 * D) return;
    int l = idx / (D * 2 * D);
    int rem = idx - l * (D * 2 * D);
    int n = rem / (2 * D);
    int k = rem - n * (2 * D);
    float v = gnn_w[(size_t)l * 2 * D * D + (size_t)k * D + n];
    wt[idx] = f2bf(v);
}

// ---------------- gather helper (fp32, 2 dims per lane, 4-deep ILP) ----------------

__device__ __forceinline__ float2 gather_mean(const float* __restrict__ h_in,
                                              const int* __restrict__ csr,
                                              int beg, int end, int d0) {
    float ax0 = 0.f, ay0 = 0.f, ax1 = 0.f, ay1 = 0.f;
    float ax2 = 0.f, ay2 = 0.f, ax3 = 0.f, ay3 = 0.f;
    int e = beg;
    for (; e + 3 < end; e += 4) {
        int s0 = csr[e], s1 = csr[e + 1], s2 = csr[e + 2], s3 = csr[e + 3];
        float2 v0 = *(const float2*)&h_in[(size_t)s0 * D + d0];
        float2 v1 = *(const float2*)&h_in[(size_t)s1 * D + d0];
        float2 v2 = *(const float2*)&h_in[(size_t)s2 * D + d0];
        float2 v3 = *(const float2*)&h_in[(size_t)s3 * D + d0];
        ax0 += v0.x; ay0 += v0.y;
        ax1 += v1.x; ay1 += v1.y;
        ax2 += v2.x; ay2 += v2.y;
        ax3 += v3.x; ay3 += v3.y;
    }
    for (; e < end; ++e) {
        float2 v = *(const float2*)&h_in[(size_t)csr[e] * D + d0];
        ax0 += v.x; ay0 += v.y;
    }
    float inv = 1.0f / fmaxf((float)(end - beg), 1.0f);
    return make_float2((ax0 + ax1 + ax2 + ax3) * inv, (ay0 + ay1 + ay2 + ay3) * inv);
}

// ---------------- input proj (v3 style, fp32 VALU) ----------------

__global__ __launch_bounds__(256) void input_proj_v3(
        const float* __restrict__ x, const float* __restrict__ w,
        const float* __restrict__ b, const float* __restrict__ gam,
        const float* __restrict__ bet, float* __restrict__ h) {
    __shared__ float xs[GB][F_IN];
    int tid = threadIdx.x;
    int wave = tid >> 6, lane = tid & 63;
    int d0 = lane << 1;
    int gbase = wave * NPW;
    int n0 = blockIdx.x * GB + gbase;

    #pragma unroll
    for (int j = 0; j < NPW; ++j) {
        int n = n0 + j;
        int ns = (n < N_NODES) ? n : (N_NODES - 1);
        xs[gbase + j][lane] = x[(size_t)ns * F_IN + lane];
    }

    float2 bb = *(const float2*)&b[d0];
    float ax[NPW], ay[NPW];
    #pragma unroll
    for (int j = 0; j < NPW; ++j) { ax[j] = bb.x; ay[j] = bb.y; }

    #pragma unroll 4
    for (int k = 0; k < F_IN; k += 4) {
        float2 w0 = *(const float2*)&w[(k + 0) * D + d0];
        float2 w1 = *(const float2*)&w[(k + 1) * D + d0];
        float2 w2 = *(const float2*)&w[(k + 2) * D + d0];
        float2 w3 = *(const float2*)&w[(k + 3) * D + d0];
        #pragma unroll
        for (int j = 0; j < NPW; ++j) {
            float4 a = *(const float4*)&xs[gbase + j][k];
            ax[j] = fmaf(a.x, w0.x, ax[j]); ay[j] = fmaf(a.x, w0.y, ay[j]);
            ax[j] = fmaf(a.y, w1.x, ax[j]); ay[j] = fmaf(a.y, w1.y, ay[j]);
            ax[j] = fmaf(a.z, w2.x, ax[j]); ay[j] = fmaf(a.z, w2.y, ay[j]);
            ax[j] = fmaf(a.w, w3.x, ax[j]); ay[j] = fmaf(a.w, w3.y, ay[j]);
        }
    }
    float2 gg = *(const float2*)&gam[d0];
    float2 bt = *(const float2*)&bet[d0];
    #pragma unroll
    for (int j = 0; j < NPW; ++j) {
        float m, istd;
        wave_meanvar(ax[j], ay[j], m, istd);
        int n = n0 + j;
        if (n < N_NODES) {
            float2 o = make_float2(gelu_exact((ax[j] - m) * istd * gg.x + bt.x),
                                   gelu_exact((ay[j] - m) * istd * gg.y + bt.y));
            *(float2*)&h[(size_t)n * D + d0] = o;
        }
    }
}

// ---------------- GNN layer v4: fp32 gather -> bf16 LDS -> MFMA GEMM -> fp32 epilogue ---

__global__ __launch_bounds__(256) void gnn_layer_v4(
        const float* __restrict__ h_in, float* __restrict__ h_out,
        const int* __restrict__ csr, const int* __restrict__ rp,
        const unsigned short* __restrict__ wt,   // [n=D][k=2D] bf16
        const float* __restrict__ bias,
        const float* __restrict__ ln1g, const float* __restrict__ ln1b,
        const float* __restrict__ ln2g, const float* __restrict__ ln2b,
        int residual) {
    __shared__ unsigned short catb[GB][CATP];   // 32 x 264 bf16 = 16.5 KB
    __shared__ float2 red1[2][GB];
    __shared__ float2 red2[2][GB];

    int tid = threadIdx.x;
    int wave = tid >> 6, lane = tid & 63;
    int nblk0 = blockIdx.x * GB;

    // ---- staging: wave owns nodes wave*8..+7; lane owns dims 2l,2l+1
    {
        int d0 = lane << 1;
        int gbase = wave * NPW;
        #pragma unroll
        for (int j = 0; j < NPW; ++j) {
            int g = gbase + j;
            int n = nblk0 + g;
            int ns = (n < N_NODES) ? n : (N_NODES - 1);
            float2 hv = *(const float2*)&h_in[(size_t)ns * D + d0];
            *(unsigned int*)&catb[g][d0] = pack2bf(hv.x, hv.y);
            int beg = rp[ns], end = rp[ns + 1];
            float2 ag = gather_mean(h_in, csr, beg, end, d0);
            *(unsigned int*)&catb[g][D + d0] = pack2bf(ag.x, ag.y);
        }
    }
    __syncthreads();

    // ---- MFMA GEMM: wave tile = 16 nodes x 64 dims
    int q = lane >> 4, c = lane & 15;
    int m0 = (wave >> 1) * 16;        // node offset within block
    int n0 = (wave & 1) * 64;         // dim offset
    f32x4 acc[4];
    #pragma unroll
    for (int t = 0; t < 4; ++t) {
        float bn = bias[n0 + t * 16 + c];
        acc[t] = (f32x4){bn, bn, bn, bn};
    }
    #pragma unroll
    for (int kk = 0; kk < 8; ++kk) {
        bf16x8 av = *(const bf16x8*)&catb[m0 + c][kk * 32 + q * 8];
        #pragma unroll
        for (int t = 0; t < 4; ++t) {
            const unsigned short* bp = &wt[(size_t)(n0 + t * 16 + c) * 256 + kk * 32 + q * 8];
            bf16x8 bv = *(const bf16x8*)bp;
            acc[t] = __builtin_amdgcn_mfma_f32_16x16x32_bf16(av, bv, acc[t], 0, 0, 0);
        }
    }

    // ---- epilogue: gelu -> LN1 -> LN2 -> (gelu+residual) in C-layout
    // lane (q,c) holds nodes m0+q*4+r (r=0..3), dims n0+t*16+c (t=0..3)
    float xv[4][4];   // [t][r]
    #pragma unroll
    for (int t = 0; t < 4; ++t)
        #pragma unroll
        for (int r = 0; r < 4; ++r) xv[t][r] = gelu_exact(acc[t][r]);

    float s[4], sq[4];
    #pragma unroll
    for (int r = 0; r < 4; ++r) {
        s[r] = xv[0][r] + xv[1][r] + xv[2][r] + xv[3][r];
        sq[r] = xv[0][r] * xv[0][r] + xv[1][r] * xv[1][r] + xv[2][r] * xv[2][r] + xv[3][r] * xv[3][r];
    }
    #pragma unroll
    for (int o = 1; o <= 8; o <<= 1)
        #pragma unroll
        for (int r = 0; r < 4; ++r) { s[r] += __shfl_xor(s[r], o); sq[r] += __shfl_xor(sq[r], o); }
    int nh = wave & 1;
    if (c == 0) {
        #pragma unroll
        for (int r = 0; r < 4; ++r) red1[nh][m0 + q * 4 + r] = make_float2(s[r], sq[r]);
    }
    __syncthreads();

    float g1v[4], b1v[4], g2v[4], b2v[4];
    #pragma unroll
    for (int t = 0; t < 4; ++t) {
        int nn = n0 + t * 16 + c;
        g1v[t] = ln1g[nn]; b1v[t] = ln1b[nn];
        g2v[t] = ln2g[nn]; b2v[t] = ln2b[nn];
    }

    float y1[4][4];
    #pragma unroll
    for (int r = 0; r < 4; ++r) {
        int m = m0 + q * 4 + r;
        float2 p0 = red1[0][m], p1 = red1[1][m];
        float mean = (p0.x + p1.x) * (1.0f / D);
        float msq  = (p0.y + p1.y) * (1.0f / D);
        float istd = rsqrtf(msq - mean * mean + 1e-5f);
        #pragma unroll
        for (int t = 0; t < 4; ++t)
            y1[t][r] = (xv[t][r] - mean) * istd * g1v[t] + b1v[t];
    }

    #pragma unroll
    for (int r = 0; r < 4; ++r) {
        s[r] = y1[0][r] + y1[1][r] + y1[2][r] + y1[3][r];
        sq[r] = y1[0][r] * y1[0][r] + y1[1][r] * y1[1][r] + y1[2][r] * y1[2][r] + y1[3][r] * y1[3][r];
    }
    #pragma unroll
    for (int o = 1; o <= 8; o <<= 1)
        #pragma unroll
        for (int r = 0; r < 4; ++r) { s[r] += __shfl_xor(s[r], o); sq[r] += __shfl_xor(sq[r], o); }
    if (c == 0) {
        #pragma unroll
        for (int r = 0; r < 4; ++r) red2[nh][m0 + q * 4 + r] = make_float2(s[r], sq[r]);
    }
    __syncthreads();

    #pragma unroll
    for (int r = 0; r < 4; ++r) {
        int m = m0 + q * 4 + r;
        int n = nblk0 + m;
        float2 p0 = red2[0][m], p1 = red2[1][m];
        float mean = (p0.x + p1.x) * (1.0f / D);
        float msq  = (p0.y + p1.y) * (1.0f / D);
        float istd = rsqrtf(msq - mean * mean + 1e-5f);
        if (n < N_NODES) {
            #pragma unroll
            for (int t = 0; t < 4; ++t) {
                int nn = n0 + t * 16 + c;
                float y2 = (y1[t][r] - mean) * istd * g2v[t] + b2v[t];
                float o = residual ? (gelu_exact(y2) + h_in[(size_t)n * D + nn]) : y2;
                h_out[(size_t)n * D + nn] = o;
            }
        }
    }
}

// ---------------- gate (v3 style) ----------------

__global__ __launch_bounds__(256) void gate_v3(
        const float* __restrict__ h, const float* __restrict__ w1,
        const float* __restrict__ b1, const float* __restrict__ w2,
        const float* __restrict__ b2, float* __restrict__ logits) {
    __shared__ float hs[GB][D];
    int tid = threadIdx.x;
    int wave = tid >> 6, lane = tid & 63;
    int d0 = lane << 1;
    int gbase = wave * NPW;
    int n0 = blockIdx.x * GB + gbase;

    #pragma unroll
    for (int j = 0; j < NPW; ++j) {
        int n = n0 + j;
        int ns = (n < N_NODES) ? n : (N_NODES - 1);
        *(float2*)&hs[gbase + j][d0] = *(const float2*)&h[(size_t)ns * D + d0];
    }

    float2 bb = *(const float2*)&b1[d0];
    float ax[NPW], ay[NPW];
    #pragma unroll
    for (int j = 0; j < NPW; ++j) { ax[j] = bb.x; ay[j] = bb.y; }

    #pragma unroll 4
    for (int k = 0; k < D; k += 4) {
        float2 w0 = *(const float2*)&w1[(k + 0) * D + d0];
        float2 wv1 = *(const float2*)&w1[(k + 1) * D + d0];
        float2 wv2 = *(const float2*)&w1[(k + 2) * D + d0];
        float2 wv3 = *(const float2*)&w1[(k + 3) * D + d0];
        #pragma unroll
        for (int j = 0; j < NPW; ++j) {
            float4 a = *(const float4*)&hs[gbase + j][k];
            ax[j] = fmaf(a.x, w0.x, ax[j]); ay[j] = fmaf(a.x, w0.y, ay[j]);
            ax[j] = fmaf(a.y, wv1.x, ax[j]); ay[j] = fmaf(a.y, wv1.y, ay[j]);
            ax[j] = fmaf(a.z, wv2.x, ax[j]); ay[j] = fmaf(a.z, wv2.y, ay[j]);
            ax[j] = fmaf(a.w, wv3.x, ax[j]); ay[j] = fmaf(a.w, wv3.y, ay[j]);
        }
    }
    float2 w2v = *(const float2*)&w2[d0];
    float bb2 = b2[0];
    #pragma unroll
    for (int j = 0; j < NPW; ++j) {
        float sv = wave_sum(tanhf(ax[j]) * w2v.x + tanhf(ay[j]) * w2v.y);
        int n = n0 + j;
        if (lane == 0 && n < N_NODES) logits[n] = sv + bb2;
    }
}

// ---------------- softmax / pool / out ----------------

__global__ void softmax_stats_kernel(const float* __restrict__ logits, float* __restrict__ stats,
                                     float* __restrict__ pooled) {
    __shared__ float sbuf[16];
    int tid = threadIdx.x;
    pooled[tid] = 0.f;  // blockDim == 1024 == B_GRAPHS * D
    float mx = -INFINITY;
    for (int i = tid; i < N_NODES; i += 1024) mx = fmaxf(mx, logits[i]);
    #pragma unroll
    for (int o = 32; o >= 1; o >>= 1) mx = fmaxf(mx, __shfl_down(mx, o));
    if ((tid & 63) == 0) sbuf[tid >> 6] = mx;
    __syncthreads();
    if (tid == 0) {
        float m = sbuf[0];
        for (int w = 1; w < 16; ++w) m = fmaxf(m, sbuf[w]);
        sbuf[0] = m;
    }
    __syncthreads();
    mx = sbuf[0];
    __syncthreads();
    float sum = 0.f;
    for (int i = tid; i < N_NODES; i += 1024) sum += expf(logits[i] - mx);
    #pragma unroll
    for (int o = 32; o >= 1; o >>= 1) sum += __shfl_down(sum, o);
    if ((tid & 63) == 0) sbuf[tid >> 6] = sum;
    __syncthreads();
    if (tid == 0) {
        float s = 0.f;
        for (int w = 0; w < 16; ++w) s += sbuf[w];
        stats[0] = mx;
        stats[1] = 1.0f / s;
    }
}

#define POOL_CHUNK 128
__global__ void gate_pool_kernel(const float* __restrict__ h, const float* __restrict__ logits,
                                 const float* __restrict__ stats, const int* __restrict__ batch,
                                 float* __restrict__ gate_out, float* __restrict__ pooled) {
    __shared__ float gs[POOL_CHUNK];
    __shared__ int bs[POOL_CHUNK];
    int n0 = blockIdx.x * POOL_CHUNK;
    int d = threadIdx.x;
    float mx = stats[0], inv = stats[1];
    int nj = n0 + d;
    if (nj < N_NODES) {
        float gv = expf(logits[nj] - mx) * inv;
        gs[d] = gv;
        bs[d] = batch[nj];
        gate_out[nj] = gv;
    }
    __syncthreads();
    int count = min(POOL_CHUNK, N_NODES - n0);
    float acc = 0.f;
    int cur = bs[0];
    for (int t = 0; t < count; ++t) {
        int bn = bs[t];
        if (bn != cur) { atomicAdd(&pooled[cur * D + d], acc); acc = 0.f; cur = bn; }
        acc += h[(size_t)(n0 + t) * D + d] * gs[t];
    }
    atomicAdd(&pooled[cur * D + d], acc);
}

__global__ void out_proj_kernel(const float* __restrict__ pooled, const float* __restrict__ w,
                                const float* __restrict__ b, const float* __restrict__ g,
                                const float* __restrict__ beta, float* __restrict__ emb) {
    __shared__ float ps[D];
    __shared__ float sbuf[2];
    int bg = blockIdx.x, d = threadIdx.x;
    ps[d] = pooled[bg * D + d];
    __syncthreads();
    float acc = b[d];
    #pragma unroll 8
    for (int k = 0; k < D; ++k) acc += ps[k] * w[k * D + d];
    float s = acc, q = acc * acc;
    #pragma unroll
    for (int o = 32; o >= 1; o >>= 1) { s += __shfl_down(s, o); q += __shfl_down(q, o); }
    if ((d & 63) == 0) { sbuf[d >> 6] = s; }
    __syncthreads();
    float fullsum = sbuf[0] + sbuf[1];
    __syncthreads();
    if ((d & 63) == 0) { sbuf[d >> 6] = q; }
    __syncthreads();
    float fullsq = sbuf[0] + sbuf[1];
    float m = fullsum * (1.0f / D);
    float var = fullsq * (1.0f / D) - m * m;
    float y = (acc - m) * rsqrtf(var + 1e-5f) * g[d] + beta[d];
    emb[bg * D + d] = gelu_exact(y);
}

extern "C" void kernel_launch(void* const* d_in, const int* in_sizes, int n_in,
                              void* d_out, int out_size, void* d_ws, size_t ws_size,
                              hipStream_t stream) {
    const float* x        = (const float*)d_in[0];
    const int*   edge     = (const int*)d_in[1];
    const int*   batch    = (const int*)d_in[2];
    const float* w_in     = (const float*)d_in[3];
    const float* b_in     = (const float*)d_in[4];
    const float* ln_in_g  = (const float*)d_in[5];
    const float* ln_in_b  = (const float*)d_in[6];
    const float* gnn_w    = (const float*)d_in[7];
    const float* gnn_b    = (const float*)d_in[8];
    const float* gnn_ln_g = (const float*)d_in[9];
    const float* gnn_ln_b = (const float*)d_in[10];
    const float* norm_g   = (const float*)d_in[11];
    const float* norm_b   = (const float*)d_in[12];
    const float* gate_w1  = (const float*)d_in[13];
    const float* gate_b1  = (const float*)d_in[14];
    const float* gate_w2  = (const float*)d_in[15];
    const float* gate_b2  = (const float*)d_in[16];
    const float* out_w    = (const float*)d_in[17];
    const float* out_b    = (const float*)d_in[18];
    const float* out_ln_g = (const float*)d_in[19];
    const float* out_ln_b = (const float*)d_in[20];

    const int* src = edge;             // edge_index[0]
    const int* dst = edge + N_EDGES;   // edge_index[1]

    float* out      = (float*)d_out;
    float* emb      = out;                               // (8,128)
    float* hA       = out + B_GRAPHS * D;                // (N,128) final h location
    float* gate_out = hA + (size_t)N_NODES * D;          // (N,)

    // workspace: hB first (N*D floats); CSR-build temporaries deg/cursor OVERLAID in hB
    float* hB       = (float*)d_ws;                      // N*D floats
    int*   deg_i    = (int*)d_ws;                        // N      (overlay)
    int*   cursor   = (int*)d_ws + N_NODES;              // N+1    (overlay)
    int*   row_ptr  = (int*)(hB + (size_t)N_NODES * D);  // N+1
    int*   csr      = row_ptr + N_NODES + 1;             // E
    float* logits   = (float*)(csr + N_EDGES);           // N
    float* pooled   = logits + N_NODES;                  // 1024
    float* stats    = pooled + B_GRAPHS * D;             // 2
    int*   partials = (int*)(stats + 2);                 // NPART
    unsigned short* wt = (unsigned short*)(((uintptr_t)(partials + NPART) + 15) & ~(uintptr_t)15);
                                                         // NLAYER*D*2D bf16 (192 KB)

    // CSR build + W prep
    zero_int_kernel<<<128, 256, 0, stream>>>(deg_i, N_NODES);
    degree_kernel<<<(N_EDGES + 255) / 256, 256, 0, stream>>>(dst, deg_i);
    scan_partials_kernel<<<NPART, SCAN_B, 0, stream>>>(deg_i, partials);
    scan_offsets_kernel<<<1, 128, 0, stream>>>(partials, row_ptr);
    scan_apply_kernel<<<NPART, SCAN_B, 0, stream>>>(deg_i, partials, row_ptr, cursor);
    fill_kernel<<<(N_EDGES + 255) / 256, 256, 0, stream>>>(src, dst, cursor, csr);
    wprep_kernel<<<(NLAYER * D * 2 * D + 255) / 256, 256, 0, stream>>>(gnn_w, wt);

    // input proj -> hB
    input_proj_v3<<<NBLK, 256, 0, stream>>>(x, w_in, b_in, ln_in_g, ln_in_b, hB);

    // ping-pong: hB -> hA -> hB -> hA  (final h lands in hA = d_out slice)
    const float* hin[3]  = {hB, hA, hB};
    float*       hout[3] = {hA, hB, hA};
    for (int i = 0; i < NLAYER; ++i) {
        gnn_layer_v4<<<NBLK, 256, 0, stream>>>(
            hin[i], hout[i], csr, row_ptr,
            wt + (size_t)i * D * 2 * D, gnn_b + i * D,
            gnn_ln_g + i * D, gnn_ln_b + i * D,
            norm_g + i * D, norm_b + i * D,
            (i < NLAYER - 1) ? 1 : 0);
    }

    gate_v3<<<NBLK, 256, 0, stream>>>(hA, gate_w1, gate_b1, gate_w2, gate_b2, logits);
    softmax_stats_kernel<<<1, 1024, 0, stream>>>(logits, stats, pooled);
    gate_pool_kernel<<<(N_NODES + POOL_CHUNK - 1) / POOL_CHUNK, POOL_CHUNK, 0, stream>>>(
        hA, logits, stats, batch, gate_out, pooled);
    out_proj_kernel<<<B_GRAPHS, D, 0, stream>>>(pooled, out_w, out_b, out_ln_g, out_ln_b, emb);
}

// Round 7
// 588.494 us; speedup vs baseline: 1.8088x; 1.1948x over previous
//
#include <hip/hip_runtime.h>
#include <math.h>

#define N_NODES 50000
#define N_EDGES 800000
#define F_IN 64
#define D 128
#define NLAYER 3
#define B_GRAPHS 8
#define GB 32               // nodes per block (4 waves; staging 8 nodes/wave; MFMA tiles 2x2)
#define NPW 8               // nodes per wave (staging)
#define NBLK ((N_NODES + GB - 1) / GB)            // 1563 (last block partial)
#define SCAN_B 512
#define NPART ((N_NODES + SCAN_B - 1) / SCAN_B)   // 98
#define AGP 136             // agg LDS row stride in ushorts (128 + 8 pad -> 16B-aligned rows)

typedef float f32x4 __attribute__((ext_vector_type(4)));
typedef short bf16x8 __attribute__((ext_vector_type(8)));

__device__ __forceinline__ float gelu_exact(float x) {
    return 0.5f * x * (1.0f + erff(x * 0.7071067811865476f));
}

__device__ __forceinline__ float wave_sum(float v) {
    #pragma unroll
    for (int o = 32; o >= 1; o >>= 1) v += __shfl_xor(v, o);
    return v;
}

__device__ __forceinline__ void wave_meanvar(float vx, float vy, float& mean, float& inv_std) {
    float s = vx + vy;
    float q = vx * vx + vy * vy;
    #pragma unroll
    for (int o = 32; o >= 1; o >>= 1) { s += __shfl_xor(s, o); q += __shfl_xor(q, o); }
    mean = s * (1.0f / D);
    float var = q * (1.0f / D) - mean * mean;
    inv_std = rsqrtf(var + 1e-5f);
}

// fp32 -> bf16 round-to-nearest-even
__device__ __forceinline__ unsigned short f2bf(float f) {
    unsigned int u = __float_as_uint(f);
    u = (u + 0x7fffu + ((u >> 16) & 1u)) >> 16;
    return (unsigned short)u;
}
__device__ __forceinline__ unsigned int pack2bf(float a, float b) {
    return (unsigned int)f2bf(a) | ((unsigned int)f2bf(b) << 16);
}
__device__ __forceinline__ float bf2f(unsigned short u) {
    return __uint_as_float((unsigned int)u << 16);
}

// ---------------- CSR build ----------------

__global__ void zero_int_kernel(int* __restrict__ p, int n) {
    int i = blockIdx.x * blockDim.x + threadIdx.x;
    int stride = gridDim.x * blockDim.x;
    for (; i < n; i += stride) p[i] = 0;
}

__global__ void degree_kernel(const int* __restrict__ dst, int* __restrict__ deg) {
    int e = blockIdx.x * blockDim.x + threadIdx.x;
    if (e < N_EDGES) atomicAdd(&deg[dst[e]], 1);
}

__global__ __launch_bounds__(SCAN_B) void scan_partials_kernel(const int* __restrict__ deg,
                                                               int* __restrict__ partials) {
    __shared__ int wsum[8];
    int tid = threadIdx.x;
    int lane = tid & 63, wave = tid >> 6;
    int i = blockIdx.x * SCAN_B + tid;
    int v = (i < N_NODES) ? deg[i] : 0;
    #pragma unroll
    for (int o = 32; o >= 1; o >>= 1) v += __shfl_xor(v, o);
    if (lane == 0) wsum[wave] = v;
    __syncthreads();
    if (tid == 0) {
        int t = 0;
        #pragma unroll
        for (int w = 0; w < 8; ++w) t += wsum[w];
        partials[blockIdx.x] = t;
    }
}

__global__ void scan_offsets_kernel(int* __restrict__ partials, int* __restrict__ row_ptr) {
    __shared__ int wtot[2];
    int tid = threadIdx.x;          // 128 threads, 2 waves
    int lane = tid & 63, wave = tid >> 6;
    int v = (tid < NPART) ? partials[tid] : 0;
    int x = v;
    #pragma unroll
    for (int o = 1; o < 64; o <<= 1) { int nb = __shfl_up(x, o); if (lane >= o) x += nb; }
    if (lane == 63) wtot[wave] = x;
    __syncthreads();
    if (wave == 1) x += wtot[0];
    if (tid < NPART) partials[tid] = x - v;       // exclusive
    if (tid == 127) row_ptr[N_NODES] = x;         // grand total
}

__global__ __launch_bounds__(SCAN_B) void scan_apply_kernel(const int* __restrict__ deg,
        const int* __restrict__ partials, int* __restrict__ row_ptr, int* __restrict__ cursor) {
    __shared__ int wsum[8];
    int tid = threadIdx.x;
    int lane = tid & 63, wave = tid >> 6;
    int i = blockIdx.x * SCAN_B + tid;
    int v = (i < N_NODES) ? deg[i] : 0;
    int x = v;
    #pragma unroll
    for (int o = 1; o < 64; o <<= 1) { int nb = __shfl_up(x, o); if (lane >= o) x += nb; }
    if (lane == 63) wsum[wave] = x;
    __syncthreads();
    int waveoff = 0;
    #pragma unroll
    for (int w = 0; w < 8; ++w) waveoff += (w < wave) ? wsum[w] : 0;
    int excl = partials[blockIdx.x] + waveoff + x - v;
    if (i < N_NODES) { row_ptr[i] = excl; cursor[i] = excl; }
}

__global__ void fill_kernel(const int* __restrict__ src, const int* __restrict__ dst,
                            int* __restrict__ cursor, int* __restrict__ csr) {
    int e = blockIdx.x * blockDim.x + threadIdx.x;
    if (e < N_EDGES) {
        int t = dst[e];
        int pos = atomicAdd(&cursor[t], 1);
        csr[pos] = src[e];
    }
}

// W prep: gnn_w fp32 [L][2D][D] -> wt bf16 [L][n=D][k=2D]; then gate_w1 [D][D] -> [n=D][k=D]
#define WT_GNN (NLAYER * D * 2 * D)
#define WT_ALL (WT_GNN + D * D)
__global__ void wprep_kernel(const float* __restrict__ gnn_w, const float* __restrict__ gate_w1,
                             unsigned short* __restrict__ wt) {
    int idx = blockIdx.x * 256 + threadIdx.x;
    if (idx >= WT_ALL) return;
    if (idx < WT_GNN) {
        int l = idx / (D * 2 * D);
        int rem = idx - l * (D * 2 * D);
        int n = rem / (2 * D);
        int k = rem - n * (2 * D);
        wt[idx] = f2bf(gnn_w[(size_t)l * 2 * D * D + (size_t)k * D + n]);
    } else {
        int rem = idx - WT_GNN;
        int n = rem / D;
        int k = rem - n * D;
        wt[idx] = f2bf(gate_w1[(size_t)k * D + n]);
    }
}

// ---------------- bf16 gather (2 dims per lane, 8-deep ILP) ----------------

__device__ __forceinline__ float2 gather_mean_bf16(
        const unsigned short* __restrict__ h16, const int* __restrict__ csr,
        int beg, int end, int lane) {
    int d0 = lane << 1;
    float sx[8], sy[8];
    #pragma unroll
    for (int i = 0; i < 8; ++i) { sx[i] = 0.f; sy[i] = 0.f; }
    int e = beg;
    for (; e + 7 < end; e += 8) {
        int idx[8];
        #pragma unroll
        for (int i = 0; i < 8; ++i) idx[i] = csr[e + i];
        #pragma unroll
        for (int i = 0; i < 8; ++i) {
            unsigned int v = *(const unsigned int*)&h16[(size_t)idx[i] * D + d0];
            sx[i] += __uint_as_float(v << 16);
            sy[i] += __uint_as_float(v & 0xffff0000u);
        }
    }
    for (; e < end; ++e) {
        unsigned int v = *(const unsigned int*)&h16[(size_t)csr[e] * D + d0];
        sx[0] += __uint_as_float(v << 16);
        sy[0] += __uint_as_float(v & 0xffff0000u);
    }
    float ax = ((sx[0] + sx[1]) + (sx[2] + sx[3])) + ((sx[4] + sx[5]) + (sx[6] + sx[7]));
    float ay = ((sy[0] + sy[1]) + (sy[2] + sy[3])) + ((sy[4] + sy[5]) + (sy[6] + sy[7]));
    float inv = 1.0f / fmaxf((float)(end - beg), 1.0f);
    return make_float2(ax * inv, ay * inv);
}

// ---------------- input proj: fp32 VALU, writes bf16 h ----------------

__global__ __launch_bounds__(256) void input_proj_v4(
        const float* __restrict__ x, const float* __restrict__ w,
        const float* __restrict__ b, const float* __restrict__ gam,
        const float* __restrict__ bet, unsigned short* __restrict__ h16) {
    __shared__ float xs[GB][F_IN];
    int tid = threadIdx.x;
    int wave = tid >> 6, lane = tid & 63;
    int d0 = lane << 1;
    int gbase = wave * NPW;
    int n0 = blockIdx.x * GB + gbase;

    #pragma unroll
    for (int j = 0; j < NPW; ++j) {
        int n = n0 + j;
        int ns = (n < N_NODES) ? n : (N_NODES - 1);
        xs[gbase + j][lane] = x[(size_t)ns * F_IN + lane];
    }

    float2 bb = *(const float2*)&b[d0];
    float ax[NPW], ay[NPW];
    #pragma unroll
    for (int j = 0; j < NPW; ++j) { ax[j] = bb.x; ay[j] = bb.y; }

    #pragma unroll 4
    for (int k = 0; k < F_IN; k += 4) {
        float2 w0 = *(const float2*)&w[(k + 0) * D + d0];
        float2 w1 = *(const float2*)&w[(k + 1) * D + d0];
        float2 w2 = *(const float2*)&w[(k + 2) * D + d0];
        float2 w3 = *(const float2*)&w[(k + 3) * D + d0];
        #pragma unroll
        for (int j = 0; j < NPW; ++j) {
            float4 a = *(const float4*)&xs[gbase + j][k];
            ax[j] = fmaf(a.x, w0.x, ax[j]); ay[j] = fmaf(a.x, w0.y, ay[j]);
            ax[j] = fmaf(a.y, w1.x, ax[j]); ay[j] = fmaf(a.y, w1.y, ay[j]);
            ax[j] = fmaf(a.z, w2.x, ax[j]); ay[j] = fmaf(a.z, w2.y, ay[j]);
            ax[j] = fmaf(a.w, w3.x, ax[j]); ay[j] = fmaf(a.w, w3.y, ay[j]);
        }
    }
    float2 gg = *(const float2*)&gam[d0];
    float2 bt = *(const float2*)&bet[d0];
    #pragma unroll
    for (int j = 0; j < NPW; ++j) {
        float m, istd;
        wave_meanvar(ax[j], ay[j], m, istd);
        int n = n0 + j;
        if (n < N_NODES) {
            float ox = gelu_exact((ax[j] - m) * istd * gg.x + bt.x);
            float oy = gelu_exact((ay[j] - m) * istd * gg.y + bt.y);
            *(unsigned int*)&h16[(size_t)n * D + d0] = pack2bf(ox, oy);
        }
    }
}

// ---------------- GNN layer v5: bf16 gather -> MFMA (A: global self + LDS agg) ----------

__global__ __launch_bounds__(256) void gnn_layer_v5(
        const unsigned short* __restrict__ h16_in, unsigned short* __restrict__ h16_out,
        float* __restrict__ hf_out,
        const int* __restrict__ csr, const int* __restrict__ rp,
        const unsigned short* __restrict__ wt,   // [n=D][k=2D] bf16
        const float* __restrict__ bias,
        const float* __restrict__ ln1g, const float* __restrict__ ln1b,
        const float* __restrict__ ln2g, const float* __restrict__ ln2b,
        int residual, int write_f32) {
    __shared__ unsigned short aggb[GB][AGP];    // 8.7 KB (agg half only)
    __shared__ float2 red1[2][GB];
    __shared__ float2 red2[2][GB];

    int tid = threadIdx.x;
    int wave = tid >> 6, lane = tid & 63;
    int nblk0 = blockIdx.x * GB;

    // ---- staging: wave owns nodes wave*8..+7; lane owns dims 2l,2l+1; agg -> LDS bf16
    {
        int gbase = wave * NPW;
        #pragma unroll
        for (int j = 0; j < NPW; ++j) {
            int g = gbase + j;
            int n = nblk0 + g;
            int ns = (n < N_NODES) ? n : (N_NODES - 1);
            int beg = rp[ns], end = rp[ns + 1];
            float2 ag = gather_mean_bf16(h16_in, csr, beg, end, lane);
            *(unsigned int*)&aggb[g][lane << 1] = pack2bf(ag.x, ag.y);
        }
    }
    __syncthreads();

    // ---- MFMA GEMM: wave tile = 16 nodes x 64 dims; K=256 (128 self from global, 128 agg LDS)
    int q = lane >> 4, c = lane & 15;
    int m0 = (wave >> 1) * 16;        // node offset within block
    int n0 = (wave & 1) * 64;         // dim offset
    int mrow = nblk0 + m0 + c;
    int mclamp = (mrow < N_NODES) ? mrow : (N_NODES - 1);
    const unsigned short* arow = h16_in + (size_t)mclamp * D;

    f32x4 acc[4];
    #pragma unroll
    for (int t = 0; t < 4; ++t) {
        float bn = bias[n0 + t * 16 + c];
        acc[t] = (f32x4){bn, bn, bn, bn};
    }
    #pragma unroll
    for (int kk = 0; kk < 4; ++kk) {      // self half: A direct from global bf16 h
        bf16x8 av = *(const bf16x8*)&arow[kk * 32 + q * 8];
        #pragma unroll
        for (int t = 0; t < 4; ++t) {
            bf16x8 bv = *(const bf16x8*)&wt[(size_t)(n0 + t * 16 + c) * 256 + kk * 32 + q * 8];
            acc[t] = __builtin_amdgcn_mfma_f32_16x16x32_bf16(av, bv, acc[t], 0, 0, 0);
        }
    }
    #pragma unroll
    for (int kk = 0; kk < 4; ++kk) {      // agg half: A from LDS
        bf16x8 av = *(const bf16x8*)&aggb[m0 + c][kk * 32 + q * 8];
        #pragma unroll
        for (int t = 0; t < 4; ++t) {
            bf16x8 bv = *(const bf16x8*)&wt[(size_t)(n0 + t * 16 + c) * 256 + 128 + kk * 32 + q * 8];
            acc[t] = __builtin_amdgcn_mfma_f32_16x16x32_bf16(av, bv, acc[t], 0, 0, 0);
        }
    }

    // ---- epilogue: gelu -> LN1 -> LN2 -> (gelu+residual) in C-layout
    // lane (q,c) holds nodes m0+q*4+r (r=0..3), dims n0+t*16+c (t=0..3)
    float xv[4][4];   // [t][r]
    #pragma unroll
    for (int t = 0; t < 4; ++t)
        #pragma unroll
        for (int r = 0; r < 4; ++r) xv[t][r] = gelu_exact(acc[t][r]);

    float s[4], sq[4];
    #pragma unroll
    for (int r = 0; r < 4; ++r) {
        s[r] = xv[0][r] + xv[1][r] + xv[2][r] + xv[3][r];
        sq[r] = xv[0][r] * xv[0][r] + xv[1][r] * xv[1][r] + xv[2][r] * xv[2][r] + xv[3][r] * xv[3][r];
    }
    #pragma unroll
    for (int o = 1; o <= 8; o <<= 1)
        #pragma unroll
        for (int r = 0; r < 4; ++r) { s[r] += __shfl_xor(s[r], o); sq[r] += __shfl_xor(sq[r], o); }
    int nh = wave & 1;
    if (c == 0) {
        #pragma unroll
        for (int r = 0; r < 4; ++r) red1[nh][m0 + q * 4 + r] = make_float2(s[r], sq[r]);
    }
    __syncthreads();

    float g1v[4], b1v[4], g2v[4], b2v[4];
    #pragma unroll
    for (int t = 0; t < 4; ++t) {
        int nn = n0 + t * 16 + c;
        g1v[t] = ln1g[nn]; b1v[t] = ln1b[nn];
        g2v[t] = ln2g[nn]; b2v[t] = ln2b[nn];
    }

    float y1[4][4];
    #pragma unroll
    for (int r = 0; r < 4; ++r) {
        int m = m0 + q * 4 + r;
        float2 p0 = red1[0][m], p1 = red1[1][m];
        float mean = (p0.x + p1.x) * (1.0f / D);
        float msq  = (p0.y + p1.y) * (1.0f / D);
        float istd = rsqrtf(msq - mean * mean + 1e-5f);
        #pragma unroll
        for (int t = 0; t < 4; ++t)
            y1[t][r] = (xv[t][r] - mean) * istd * g1v[t] + b1v[t];
    }

    #pragma unroll
    for (int r = 0; r < 4; ++r) {
        s[r] = y1[0][r] + y1[1][r] + y1[2][r] + y1[3][r];
        sq[r] = y1[0][r] * y1[0][r] + y1[1][r] * y1[1][r] + y1[2][r] * y1[2][r] + y1[3][r] * y1[3][r];
    }
    #pragma unroll
    for (int o = 1; o <= 8; o <<= 1)
        #pragma unroll
        for (int r = 0; r < 4; ++r) { s[r] += __shfl_xor(s[r], o); sq[r] += __shfl_xor(sq[r], o); }
    if (c == 0) {
        #pragma unroll
        for (int r = 0; r < 4; ++r) red2[nh][m0 + q * 4 + r] = make_float2(s[r], sq[r]);
    }
    __syncthreads();

    #pragma unroll
    for (int r = 0; r < 4; ++r) {
        int m = m0 + q * 4 + r;
        int n = nblk0 + m;
        float2 p0 = red2[0][m], p1 = red2[1][m];
        float mean = (p0.x + p1.x) * (1.0f / D);
        float msq  = (p0.y + p1.y) * (1.0f / D);
        float istd = rsqrtf(msq - mean * mean + 1e-5f);
        if (n < N_NODES) {
            #pragma unroll
            for (int t = 0; t < 4; ++t) {
                int nn = n0 + t * 16 + c;
                float y2 = (y1[t][r] - mean) * istd * g2v[t] + b2v[t];
                float o = residual ? (gelu_exact(y2) + bf2f(h16_in[(size_t)n * D + nn])) : y2;
                h16_out[(size_t)n * D + nn] = f2bf(o);
                if (write_f32) hf_out[(size_t)n * D + nn] = o;
            }
        }
    }
}

// ---------------- gate v4: MFMA, A/B straight from global bf16 ----------------

__global__ __launch_bounds__(256) void gate_v4(
        const unsigned short* __restrict__ h16, const unsigned short* __restrict__ wtg,
        const float* __restrict__ b1, const float* __restrict__ w2,
        const float* __restrict__ b2, float* __restrict__ logits) {
    __shared__ float redg[2][GB];
    int tid = threadIdx.x;
    int wave = tid >> 6, lane = tid & 63;
    int nblk0 = blockIdx.x * GB;
    int q = lane >> 4, c = lane & 15;
    int m0 = (wave >> 1) * 16;
    int n0 = (wave & 1) * 64;
    int mrow = nblk0 + m0 + c;
    int mclamp = (mrow < N_NODES) ? mrow : (N_NODES - 1);
    const unsigned short* arow = h16 + (size_t)mclamp * D;

    f32x4 acc[4];
    #pragma unroll
    for (int t = 0; t < 4; ++t) {
        float bn = b1[n0 + t * 16 + c];
        acc[t] = (f32x4){bn, bn, bn, bn};
    }
    #pragma unroll
    for (int kk = 0; kk < 4; ++kk) {
        bf16x8 av = *(const bf16x8*)&arow[kk * 32 + q * 8];
        #pragma unroll
        for (int t = 0; t < 4; ++t) {
            bf16x8 bv = *(const bf16x8*)&wtg[(size_t)(n0 + t * 16 + c) * 128 + kk * 32 + q * 8];
            acc[t] = __builtin_amdgcn_mfma_f32_16x16x32_bf16(av, bv, acc[t], 0, 0, 0);
        }
    }
    // s[r] = sum over this wave's 64 dims of tanh(z)*w2
    float w2v[4];
    #pragma unroll
    for (int t = 0; t < 4; ++t) w2v[t] = w2[n0 + t * 16 + c];
    float s[4];
    #pragma unroll
    for (int r = 0; r < 4; ++r) {
        s[r] = tanhf(acc[0][r]) * w2v[0] + tanhf(acc[1][r]) * w2v[1]
             + tanhf(acc[2][r]) * w2v[2] + tanhf(acc[3][r]) * w2v[3];
    }
    #pragma unroll
    for (int o = 1; o <= 8; o <<= 1)
        #pragma unroll
        for (int r = 0; r < 4; ++r) s[r] += __shfl_xor(s[r], o);
    if (c == 0) {
        #pragma unroll
        for (int r = 0; r < 4; ++r) redg[wave & 1][m0 + q * 4 + r] = s[r];
    }
    __syncthreads();
    if ((wave & 1) == 0 && c == 0) {
        float bb2 = b2[0];
        #pragma unroll
        for (int r = 0; r < 4; ++r) {
            int m = m0 + q * 4 + r;
            int n = nblk0 + m;
            if (n < N_NODES) logits[n] = redg[0][m] + redg[1][m] + bb2;
        }
    }
}

// ---------------- softmax / pool / out ----------------

__global__ void softmax_stats_kernel(const float* __restrict__ logits, float* __restrict__ stats,
                                     float* __restrict__ pooled) {
    __shared__ float sbuf[16];
    int tid = threadIdx.x;
    pooled[tid] = 0.f;  // blockDim == 1024 == B_GRAPHS * D
    float mx = -INFINITY;
    for (int i = tid; i < N_NODES; i += 1024) mx = fmaxf(mx, logits[i]);
    #pragma unroll
    for (int o = 32; o >= 1; o >>= 1) mx = fmaxf(mx, __shfl_down(mx, o));
    if ((tid & 63) == 0) sbuf[tid >> 6] = mx;
    __syncthreads();
    if (tid == 0) {
        float m = sbuf[0];
        for (int w = 1; w < 16; ++w) m = fmaxf(m, sbuf[w]);
        sbuf[0] = m;
    }
    __syncthreads();
    mx = sbuf[0];
    __syncthreads();
    float sum = 0.f;
    for (int i = tid; i < N_NODES; i += 1024) sum += expf(logits[i] - mx);
    #pragma unroll
    for (int o = 32; o >= 1; o >>= 1) sum += __shfl_down(sum, o);
    if ((tid & 63) == 0) sbuf[tid >> 6] = sum;
    __syncthreads();
    if (tid == 0) {
        float s = 0.f;
        for (int w = 0; w < 16; ++w) s += sbuf[w];
        stats[0] = mx;
        stats[1] = 1.0f / s;
    }
}

#define POOL_CHUNK 128
__global__ void gate_pool_kernel(const float* __restrict__ h, const float* __restrict__ logits,
                                 const float* __restrict__ stats, const int* __restrict__ batch,
                                 float* __restrict__ gate_out, float* __restrict__ pooled) {
    __shared__ float gs[POOL_CHUNK];
    __shared__ int bs[POOL_CHUNK];
    int n0 = blockIdx.x * POOL_CHUNK;
    int d = threadIdx.x;
    float mx = stats[0], inv = stats[1];
    int nj = n0 + d;
    if (nj < N_NODES) {
        float gv = expf(logits[nj] - mx) * inv;
        gs[d] = gv;
        bs[d] = batch[nj];
        gate_out[nj] = gv;
    }
    __syncthreads();
    int count = min(POOL_CHUNK, N_NODES - n0);
    float acc = 0.f;
    int cur = bs[0];
    int t = 0;
    for (; t + 3 < count; t += 4) {
        float h0 = h[(size_t)(n0 + t + 0) * D + d];
        float h1 = h[(size_t)(n0 + t + 1) * D + d];
        float h2 = h[(size_t)(n0 + t + 2) * D + d];
        float h3 = h[(size_t)(n0 + t + 3) * D + d];
        int b0 = bs[t], b1 = bs[t + 1], b2 = bs[t + 2], b3 = bs[t + 3];
        if (b0 != cur) { atomicAdd(&pooled[cur * D + d], acc); acc = 0.f; cur = b0; }
        acc = fmaf(h0, gs[t], acc);
        if (b1 != cur) { atomicAdd(&pooled[cur * D + d], acc); acc = 0.f; cur = b1; }
        acc = fmaf(h1, gs[t + 1], acc);
        if (b2 != cur) { atomicAdd(&pooled[cur * D + d], acc); acc = 0.f; cur = b2; }
        acc = fmaf(h2, gs[t + 2], acc);
        if (b3 != cur) { atomicAdd(&pooled[cur * D + d], acc); acc = 0.f; cur = b3; }
        acc = fmaf(h3, gs[t + 3], acc);
    }
    for (; t < count; ++t) {
        int bn = bs[t];
        if (bn != cur) { atomicAdd(&pooled[cur * D + d], acc); acc = 0.f; cur = bn; }
        acc = fmaf(h[(size_t)(n0 + t) * D + d], gs[t], acc);
    }
    atomicAdd(&pooled[cur * D + d], acc);
}

__global__ void out_proj_kernel(const float* __restrict__ pooled, const float* __restrict__ w,
                                const float* __restrict__ b, const float* __restrict__ g,
                                const float* __restrict__ beta, float* __restrict__ emb) {
    __shared__ float ps[D];
    __shared__ float sbuf[2];
    int bg = blockIdx.x, d = threadIdx.x;
    ps[d] = pooled[bg * D + d];
    __syncthreads();
    float acc = b[d];
    #pragma unroll 8
    for (int k = 0; k < D; ++k) acc += ps[k] * w[k * D + d];
    float s = acc, q = acc * acc;
    #pragma unroll
    for (int o = 32; o >= 1; o >>= 1) { s += __shfl_down(s, o); q += __shfl_down(q, o); }
    if ((d & 63) == 0) { sbuf[d >> 6] = s; }
    __syncthreads();
    float fullsum = sbuf[0] + sbuf[1];
    __syncthreads();
    if ((d & 63) == 0) { sbuf[d >> 6] = q; }
    __syncthreads();
    float fullsq = sbuf[0] + sbuf[1];
    float m = fullsum * (1.0f / D);
    float var = fullsq * (1.0f / D) - m * m;
    float y = (acc - m) * rsqrtf(var + 1e-5f) * g[d] + beta[d];
    emb[bg * D + d] = gelu_exact(y);
}

extern "C" void kernel_launch(void* const* d_in, const int* in_sizes, int n_in,
                              void* d_out, int out_size, void* d_ws, size_t ws_size,
                              hipStream_t stream) {
    const float* x        = (const float*)d_in[0];
    const int*   edge     = (const int*)d_in[1];
    const int*   batch    = (const int*)d_in[2];
    const float* w_in     = (const float*)d_in[3];
    const float* b_in     = (const float*)d_in[4];
    const float* ln_in_g  = (const float*)d_in[5];
    const float* ln_in_b  = (const float*)d_in[6];
    const float* gnn_w    = (const float*)d_in[7];
    const float* gnn_b    = (const float*)d_in[8];
    const float* gnn_ln_g = (const float*)d_in[9];
    const float* gnn_ln_b = (const float*)d_in[10];
    const float* norm_g   = (const float*)d_in[11];
    const float* norm_b   = (const float*)d_in[12];
    const float* gate_w1  = (const float*)d_in[13];
    const float* gate_b1  = (const float*)d_in[14];
    const float* gate_w2  = (const float*)d_in[15];
    const float* gate_b2  = (const float*)d_in[16];
    const float* out_w    = (const float*)d_in[17];
    const float* out_b    = (const float*)d_in[18];
    const float* out_ln_g = (const float*)d_in[19];
    const float* out_ln_b = (const float*)d_in[20];

    const int* src = edge;             // edge_index[0]
    const int* dst = edge + N_EDGES;   // edge_index[1]

    float* out      = (float*)d_out;
    float* emb      = out;                               // (8,128)
    float* hA       = out + B_GRAPHS * D;                // (N,128) final h (fp32)
    float* gate_out = hA + (size_t)N_NODES * D;          // (N,)

    // workspace: bf16 ping-pong h16A/h16B; CSR temporaries deg/cursor overlaid in h16A
    // (deg/cursor die after fill_kernel; h16A first written by layer 0)
    unsigned short* h16A = (unsigned short*)d_ws;        // N*D bf16
    unsigned short* h16B = h16A + (size_t)N_NODES * D;   // N*D bf16
    int*   deg_i    = (int*)d_ws;                        // N      (overlay in h16A)
    int*   cursor   = (int*)d_ws + N_NODES;              // N+1    (overlay in h16A)
    int*   row_ptr  = (int*)(h16B + (size_t)N_NODES * D);// N+1
    int*   csr      = row_ptr + N_NODES + 1;             // E
    float* logits   = (float*)(csr + N_EDGES);           // N
    float* pooled   = logits + N_NODES;                  // 1024
    float* stats    = pooled + B_GRAPHS * D;             // 2
    int*   partials = (int*)(stats + 2);                 // NPART
    unsigned short* wt = (unsigned short*)(((uintptr_t)(partials + NPART) + 15) & ~(uintptr_t)15);
    unsigned short* wtg = wt + WT_GNN;                   // gate w1 bf16 [n=D][k=D]

    // CSR build + W prep
    zero_int_kernel<<<128, 256, 0, stream>>>(deg_i, N_NODES);
    degree_kernel<<<(N_EDGES + 255) / 256, 256, 0, stream>>>(dst, deg_i);
    scan_partials_kernel<<<NPART, SCAN_B, 0, stream>>>(deg_i, partials);
    scan_offsets_kernel<<<1, 128, 0, stream>>>(partials, row_ptr);
    scan_apply_kernel<<<NPART, SCAN_B, 0, stream>>>(deg_i, partials, row_ptr, cursor);
    fill_kernel<<<(N_EDGES + 255) / 256, 256, 0, stream>>>(src, dst, cursor, csr);
    wprep_kernel<<<(WT_ALL + 255) / 256, 256, 0, stream>>>(gnn_w, gate_w1, wt);

    // input proj -> h16B (bf16)
    input_proj_v4<<<NBLK, 256, 0, stream>>>(x, w_in, b_in, ln_in_g, ln_in_b, h16B);

    // layers: h16B -> h16A -> h16B -> (h16A + hA fp32)
    const unsigned short* hin[3]  = {h16B, h16A, h16B};
    unsigned short*       hout[3] = {h16A, h16B, h16A};
    for (int i = 0; i < NLAYER; ++i) {
        gnn_layer_v5<<<NBLK, 256, 0, stream>>>(
            hin[i], hout[i], hA, csr, row_ptr,
            wt + (size_t)i * D * 2 * D, gnn_b + i * D,
            gnn_ln_g + i * D, gnn_ln_b + i * D,
            norm_g + i * D, norm_b + i * D,
            (i < NLAYER - 1) ? 1 : 0, (i == NLAYER - 1) ? 1 : 0);
    }

    gate_v4<<<NBLK, 256, 0, stream>>>(h16A, wtg, gate_b1, gate_w2, gate_b2, logits);
    softmax_stats_kernel<<<1, 1024, 0, stream>>>(logits, stats, pooled);
    gate_pool_kernel<<<(N_NODES + POOL_CHUNK - 1) / POOL_CHUNK, POOL_CHUNK, 0, stream>>>(
        hA, logits, stats, batch, gate_out, pooled);
    out_proj_kernel<<<B_GRAPHS, D, 0, stream>>>(pooled, out_w, out_b, out_ln_g, out_ln_b, emb);
}

// Round 8
// 513.874 us; speedup vs baseline: 2.0714x; 1.1452x over previous
//
#include <hip/hip_runtime.h>
#include <math.h>

#define N_NODES 50000
#define N_EDGES 800000
#define F_IN 64
#define D 128
#define NLAYER 3
#define B_GRAPHS 8
#define GB 32               // nodes per block (4 waves; staging 8 nodes/wave; MFMA tiles 2x2)
#define NPW 8               // nodes per wave (staging)
#define NBLK ((N_NODES + GB - 1) / GB)            // 1563 (last block partial)
#define SCAN_B 512
#define NPART ((N_NODES + SCAN_B - 1) / SCAN_B)   // 98
#define AGP 136             // agg LDS row stride in ushorts (128 + 8 pad -> 16B-aligned rows)

typedef float f32x4 __attribute__((ext_vector_type(4)));
typedef short bf16x8 __attribute__((ext_vector_type(8)));

__device__ __forceinline__ float gelu_exact(float x) {
    return 0.5f * x * (1.0f + erff(x * 0.7071067811865476f));
}

__device__ __forceinline__ void wave_meanvar(float vx, float vy, float& mean, float& inv_std) {
    float s = vx + vy;
    float q = vx * vx + vy * vy;
    #pragma unroll
    for (int o = 32; o >= 1; o >>= 1) { s += __shfl_xor(s, o); q += __shfl_xor(q, o); }
    mean = s * (1.0f / D);
    float var = q * (1.0f / D) - mean * mean;
    inv_std = rsqrtf(var + 1e-5f);
}

// fp32 -> bf16 round-to-nearest-even
__device__ __forceinline__ unsigned short f2bf(float f) {
    unsigned int u = __float_as_uint(f);
    u = (u + 0x7fffu + ((u >> 16) & 1u)) >> 16;
    return (unsigned short)u;
}
__device__ __forceinline__ unsigned int pack2bf(float a, float b) {
    return (unsigned int)f2bf(a) | ((unsigned int)f2bf(b) << 16);
}
__device__ __forceinline__ float bf2f(unsigned short u) {
    return __uint_as_float((unsigned int)u << 16);
}

// ---------------- CSR build ----------------

__global__ void zero_int_kernel(int* __restrict__ p, int n) {
    int i = blockIdx.x * blockDim.x + threadIdx.x;
    int stride = gridDim.x * blockDim.x;
    for (; i < n; i += stride) p[i] = 0;
}

__global__ void degree_kernel(const int* __restrict__ dst, int* __restrict__ deg) {
    int e = blockIdx.x * blockDim.x + threadIdx.x;
    if (e < N_EDGES) atomicAdd(&deg[dst[e]], 1);
}

__global__ __launch_bounds__(SCAN_B) void scan_partials_kernel(const int* __restrict__ deg,
                                                               int* __restrict__ partials) {
    __shared__ int wsum[8];
    int tid = threadIdx.x;
    int lane = tid & 63, wave = tid >> 6;
    int i = blockIdx.x * SCAN_B + tid;
    int v = (i < N_NODES) ? deg[i] : 0;
    #pragma unroll
    for (int o = 32; o >= 1; o >>= 1) v += __shfl_xor(v, o);
    if (lane == 0) wsum[wave] = v;
    __syncthreads();
    if (tid == 0) {
        int t = 0;
        #pragma unroll
        for (int w = 0; w < 8; ++w) t += wsum[w];
        partials[blockIdx.x] = t;
    }
}

__global__ void scan_offsets_kernel(int* __restrict__ partials, int* __restrict__ row_ptr) {
    __shared__ int wtot[2];
    int tid = threadIdx.x;          // 128 threads, 2 waves
    int lane = tid & 63, wave = tid >> 6;
    int v = (tid < NPART) ? partials[tid] : 0;
    int x = v;
    #pragma unroll
    for (int o = 1; o < 64; o <<= 1) { int nb = __shfl_up(x, o); if (lane >= o) x += nb; }
    if (lane == 63) wtot[wave] = x;
    __syncthreads();
    if (wave == 1) x += wtot[0];
    if (tid < NPART) partials[tid] = x - v;       // exclusive
    if (tid == 127) row_ptr[N_NODES] = x;         // grand total
}

__global__ __launch_bounds__(SCAN_B) void scan_apply_kernel(const int* __restrict__ deg,
        const int* __restrict__ partials, int* __restrict__ row_ptr, int* __restrict__ cursor) {
    __shared__ int wsum[8];
    int tid = threadIdx.x;
    int lane = tid & 63, wave = tid >> 6;
    int i = blockIdx.x * SCAN_B + tid;
    int v = (i < N_NODES) ? deg[i] : 0;
    int x = v;
    #pragma unroll
    for (int o = 1; o < 64; o <<= 1) { int nb = __shfl_up(x, o); if (lane >= o) x += nb; }
    if (lane == 63) wsum[wave] = x;
    __syncthreads();
    int waveoff = 0;
    #pragma unroll
    for (int w = 0; w < 8; ++w) waveoff += (w < wave) ? wsum[w] : 0;
    int excl = partials[blockIdx.x] + waveoff + x - v;
    if (i < N_NODES) { row_ptr[i] = excl; cursor[i] = excl; }
}

__global__ void fill_kernel(const int* __restrict__ src, const int* __restrict__ dst,
                            int* __restrict__ cursor, int* __restrict__ csr) {
    int e = blockIdx.x * blockDim.x + threadIdx.x;
    if (e < N_EDGES) {
        int t = dst[e];
        int pos = atomicAdd(&cursor[t], 1);
        csr[pos] = src[e];
    }
}

// W prep: gnn_w fp32 [L][2D][D] -> wt bf16 [L][n=D][k=2D]; then gate_w1 [D][D] -> [n=D][k=D]
#define WT_GNN (NLAYER * D * 2 * D)
#define WT_ALL (WT_GNN + D * D)
__global__ void wprep_kernel(const float* __restrict__ gnn_w, const float* __restrict__ gate_w1,
                             unsigned short* __restrict__ wt) {
    int idx = blockIdx.x * 256 + threadIdx.x;
    if (idx >= WT_ALL) return;
    if (idx < WT_GNN) {
        int l = idx / (D * 2 * D);
        int rem = idx - l * (D * 2 * D);
        int n = rem / (2 * D);
        int k = rem - n * (2 * D);
        wt[idx] = f2bf(gnn_w[(size_t)l * 2 * D * D + (size_t)k * D + n]);
    } else {
        int rem = idx - WT_GNN;
        int n = rem / D;
        int k = rem - n * D;
        wt[idx] = f2bf(gate_w1[(size_t)k * D + n]);
    }
}

// ---------------- input proj: fp32 VALU, writes bf16 h ----------------

__global__ __launch_bounds__(256) void input_proj_v4(
        const float* __restrict__ x, const float* __restrict__ w,
        const float* __restrict__ b, const float* __restrict__ gam,
        const float* __restrict__ bet, unsigned short* __restrict__ h16) {
    __shared__ float xs[GB][F_IN];
    int tid = threadIdx.x;
    int wave = tid >> 6, lane = tid & 63;
    int d0 = lane << 1;
    int gbase = wave * NPW;
    int n0 = blockIdx.x * GB + gbase;

    #pragma unroll
    for (int j = 0; j < NPW; ++j) {
        int n = n0 + j;
        int ns = (n < N_NODES) ? n : (N_NODES - 1);
        xs[gbase + j][lane] = x[(size_t)ns * F_IN + lane];
    }

    float2 bb = *(const float2*)&b[d0];
    float ax[NPW], ay[NPW];
    #pragma unroll
    for (int j = 0; j < NPW; ++j) { ax[j] = bb.x; ay[j] = bb.y; }

    #pragma unroll 4
    for (int k = 0; k < F_IN; k += 4) {
        float2 w0 = *(const float2*)&w[(k + 0) * D + d0];
        float2 w1 = *(const float2*)&w[(k + 1) * D + d0];
        float2 w2 = *(const float2*)&w[(k + 2) * D + d0];
        float2 w3 = *(const float2*)&w[(k + 3) * D + d0];
        #pragma unroll
        for (int j = 0; j < NPW; ++j) {
            float4 a = *(const float4*)&xs[gbase + j][k];
            ax[j] = fmaf(a.x, w0.x, ax[j]); ay[j] = fmaf(a.x, w0.y, ay[j]);
            ax[j] = fmaf(a.y, w1.x, ax[j]); ay[j] = fmaf(a.y, w1.y, ay[j]);
            ax[j] = fmaf(a.z, w2.x, ax[j]); ay[j] = fmaf(a.z, w2.y, ay[j]);
            ax[j] = fmaf(a.w, w3.x, ax[j]); ay[j] = fmaf(a.w, w3.y, ay[j]);
        }
    }
    float2 gg = *(const float2*)&gam[d0];
    float2 bt = *(const float2*)&bet[d0];
    #pragma unroll
    for (int j = 0; j < NPW; ++j) {
        float m, istd;
        wave_meanvar(ax[j], ay[j], m, istd);
        int n = n0 + j;
        if (n < N_NODES) {
            float ox = gelu_exact((ax[j] - m) * istd * gg.x + bt.x);
            float oy = gelu_exact((ay[j] - m) * istd * gg.y + bt.y);
            *(unsigned int*)&h16[(size_t)n * D + d0] = pack2bf(ox, oy);
        }
    }
}

// ---------------- GNN layer v6: edge-parallel bf16 gather -> MFMA -> fp32 epilogue ------

__device__ __forceinline__ void acc_row(float acc[8], bf16x8 v) {
    #pragma unroll
    for (int i = 0; i < 8; ++i)
        acc[i] += __uint_as_float(((unsigned int)(unsigned short)v[i]) << 16);
}

__global__ __launch_bounds__(256) void gnn_layer_v6(
        const unsigned short* __restrict__ h16_in, unsigned short* __restrict__ h16_out,
        float* __restrict__ hf_out,
        const int* __restrict__ csr, const int* __restrict__ rp,
        const unsigned short* __restrict__ wt,   // [n=D][k=2D] bf16
        const float* __restrict__ bias,
        const float* __restrict__ ln1g, const float* __restrict__ ln1b,
        const float* __restrict__ ln2g, const float* __restrict__ ln2b,
        int residual, int write_f32) {
    __shared__ unsigned short aggb[GB][AGP];    // 8.7 KB (agg half only)
    __shared__ float2 red1[2][GB];
    __shared__ float2 red2[2][GB];

    int tid = threadIdx.x;
    int wave = tid >> 6, lane = tid & 63;
    int nblk0 = blockIdx.x * GB;
    int gbase = wave * NPW;

    // ---- staging: edge-parallel gather. lane: er = edge slot (0..3), dg = dim group (0..15)
    {
        int er = lane >> 4, dg = lane & 15;
        // phase 1: row_ptr for the wave's 8 nodes (wave-uniform -> scalarized)
        int begs[NPW], ends[NPW];
        #pragma unroll
        for (int j = 0; j < NPW; ++j) {
            int n = nblk0 + gbase + j;
            int ns = (n < N_NODES) ? n : (N_NODES - 1);
            begs[j] = rp[ns];
            ends[j] = rp[ns + 1];
        }
        // phase 2: prefetch batch-1 csr indices for all 8 nodes (32 loads in flight)
        int idx1[NPW][4];
        #pragma unroll
        for (int j = 0; j < NPW; ++j) {
            int beg = begs[j], end = ends[j];
            int fb = (end > beg) ? (end - 1) : 0;
            #pragma unroll
            for (int t = 0; t < 4; ++t) {
                int ee = beg + er + 4 * t;
                idx1[j][t] = csr[(ee < end) ? ee : fb];
            }
        }
        // phase 3: per node: row loads + reduce + LDS write
        #pragma unroll
        for (int j = 0; j < NPW; ++j) {
            int g = gbase + j;
            int beg = begs[j], end = ends[j];
            float acc[8];
            #pragma unroll
            for (int i = 0; i < 8; ++i) acc[i] = 0.f;
            #pragma unroll
            for (int t = 0; t < 4; ++t) {
                bf16x8 v = *(const bf16x8*)&h16_in[(size_t)idx1[j][t] * D + dg * 8];
                if (beg + er + 4 * t < end) acc_row(acc, v);
            }
            if (end - beg > 16) {               // wave-uniform branch
                int fb = end - 1;
                int idx2[4];
                #pragma unroll
                for (int t = 4; t < 8; ++t) {
                    int ee = beg + er + 4 * t;
                    idx2[t - 4] = csr[(ee < end) ? ee : fb];
                }
                #pragma unroll
                for (int t = 4; t < 8; ++t) {
                    bf16x8 v = *(const bf16x8*)&h16_in[(size_t)idx2[t - 4] * D + dg * 8];
                    if (beg + er + 4 * t < end) acc_row(acc, v);
                }
                for (int ee = beg + er + 32; ee < end; ee += 4) {   // rare: deg > 32
                    bf16x8 v = *(const bf16x8*)&h16_in[(size_t)csr[ee] * D + dg * 8];
                    acc_row(acc, v);
                }
            }
            // butterfly across er groups (lane bits 4,5)
            #pragma unroll
            for (int i = 0; i < 8; ++i) {
                acc[i] += __shfl_xor(acc[i], 16);
                acc[i] += __shfl_xor(acc[i], 32);
            }
            float inv = 1.0f / fmaxf((float)(end - beg), 1.0f);
            if (er == 0) {
                bf16x8 o;
                #pragma unroll
                for (int i = 0; i < 8; ++i) o[i] = (short)f2bf(acc[i] * inv);
                *(bf16x8*)&aggb[g][dg * 8] = o;
            }
        }
    }
    __syncthreads();

    // ---- MFMA GEMM: wave tile = 16 nodes x 64 dims; K=256 (128 self from global, 128 agg LDS)
    int q = lane >> 4, c = lane & 15;
    int m0 = (wave >> 1) * 16;        // node offset within block
    int n0 = (wave & 1) * 64;         // dim offset
    int mrow = nblk0 + m0 + c;
    int mclamp = (mrow < N_NODES) ? mrow : (N_NODES - 1);
    const unsigned short* arow = h16_in + (size_t)mclamp * D;

    f32x4 acc[4];
    #pragma unroll
    for (int t = 0; t < 4; ++t) {
        float bn = bias[n0 + t * 16 + c];
        acc[t] = (f32x4){bn, bn, bn, bn};
    }
    #pragma unroll
    for (int kk = 0; kk < 4; ++kk) {      // self half: A direct from global bf16 h
        bf16x8 av = *(const bf16x8*)&arow[kk * 32 + q * 8];
        #pragma unroll
        for (int t = 0; t < 4; ++t) {
            bf16x8 bv = *(const bf16x8*)&wt[(size_t)(n0 + t * 16 + c) * 256 + kk * 32 + q * 8];
            acc[t] = __builtin_amdgcn_mfma_f32_16x16x32_bf16(av, bv, acc[t], 0, 0, 0);
        }
    }
    #pragma unroll
    for (int kk = 0; kk < 4; ++kk) {      // agg half: A from LDS
        bf16x8 av = *(const bf16x8*)&aggb[m0 + c][kk * 32 + q * 8];
        #pragma unroll
        for (int t = 0; t < 4; ++t) {
            bf16x8 bv = *(const bf16x8*)&wt[(size_t)(n0 + t * 16 + c) * 256 + 128 + kk * 32 + q * 8];
            acc[t] = __builtin_amdgcn_mfma_f32_16x16x32_bf16(av, bv, acc[t], 0, 0, 0);
        }
    }

    // ---- epilogue: gelu -> LN1 -> LN2 -> (gelu+residual) in C-layout
    float xv[4][4];   // [t][r]
    #pragma unroll
    for (int t = 0; t < 4; ++t)
        #pragma unroll
        for (int r = 0; r < 4; ++r) xv[t][r] = gelu_exact(acc[t][r]);

    float s[4], sq[4];
    #pragma unroll
    for (int r = 0; r < 4; ++r) {
        s[r] = xv[0][r] + xv[1][r] + xv[2][r] + xv[3][r];
        sq[r] = xv[0][r] * xv[0][r] + xv[1][r] * xv[1][r] + xv[2][r] * xv[2][r] + xv[3][r] * xv[3][r];
    }
    #pragma unroll
    for (int o = 1; o <= 8; o <<= 1)
        #pragma unroll
        for (int r = 0; r < 4; ++r) { s[r] += __shfl_xor(s[r], o); sq[r] += __shfl_xor(sq[r], o); }
    int nh = wave & 1;
    if (c == 0) {
        #pragma unroll
        for (int r = 0; r < 4; ++r) red1[nh][m0 + q * 4 + r] = make_float2(s[r], sq[r]);
    }
    __syncthreads();

    float g1v[4], b1v[4], g2v[4], b2v[4];
    #pragma unroll
    for (int t = 0; t < 4; ++t) {
        int nn = n0 + t * 16 + c;
        g1v[t] = ln1g[nn]; b1v[t] = ln1b[nn];
        g2v[t] = ln2g[nn]; b2v[t] = ln2b[nn];
    }

    float y1[4][4];
    #pragma unroll
    for (int r = 0; r < 4; ++r) {
        int m = m0 + q * 4 + r;
        float2 p0 = red1[0][m], p1 = red1[1][m];
        float mean = (p0.x + p1.x) * (1.0f / D);
        float msq  = (p0.y + p1.y) * (1.0f / D);
        float istd = rsqrtf(msq - mean * mean + 1e-5f);
        #pragma unroll
        for (int t = 0; t < 4; ++t)
            y1[t][r] = (xv[t][r] - mean) * istd * g1v[t] + b1v[t];
    }

    #pragma unroll
    for (int r = 0; r < 4; ++r) {
        s[r] = y1[0][r] + y1[1][r] + y1[2][r] + y1[3][r];
        sq[r] = y1[0][r] * y1[0][r] + y1[1][r] * y1[1][r] + y1[2][r] * y1[2][r] + y1[3][r] * y1[3][r];
    }
    #pragma unroll
    for (int o = 1; o <= 8; o <<= 1)
        #pragma unroll
        for (int r = 0; r < 4; ++r) { s[r] += __shfl_xor(s[r], o); sq[r] += __shfl_xor(sq[r], o); }
    if (c == 0) {
        #pragma unroll
        for (int r = 0; r < 4; ++r) red2[nh][m0 + q * 4 + r] = make_float2(s[r], sq[r]);
    }
    __syncthreads();

    #pragma unroll
    for (int r = 0; r < 4; ++r) {
        int m = m0 + q * 4 + r;
        int n = nblk0 + m;
        float2 p0 = red2[0][m], p1 = red2[1][m];
        float mean = (p0.x + p1.x) * (1.0f / D);
        float msq  = (p0.y + p1.y) * (1.0f / D);
        float istd = rsqrtf(msq - mean * mean + 1e-5f);
        if (n < N_NODES) {
            #pragma unroll
            for (int t = 0; t < 4; ++t) {
                int nn = n0 + t * 16 + c;
                float y2 = (y1[t][r] - mean) * istd * g2v[t] + b2v[t];
                float o = residual ? (gelu_exact(y2) + bf2f(h16_in[(size_t)n * D + nn])) : y2;
                h16_out[(size_t)n * D + nn] = f2bf(o);
                if (write_f32) hf_out[(size_t)n * D + nn] = o;
            }
        }
    }
}

// ---------------- gate v5: MFMA + fused per-block softmax partials ----------------

__global__ __launch_bounds__(256) void gate_v5(
        const unsigned short* __restrict__ h16, const unsigned short* __restrict__ wtg,
        const float* __restrict__ b1, const float* __restrict__ w2,
        const float* __restrict__ b2, float* __restrict__ logits,
        float2* __restrict__ gpart) {
    __shared__ float redg[2][GB];
    __shared__ float lg[GB];
    int tid = threadIdx.x;
    int wave = tid >> 6, lane = tid & 63;
    int nblk0 = blockIdx.x * GB;
    int q = lane >> 4, c = lane & 15;
    int m0 = (wave >> 1) * 16;
    int n0 = (wave & 1) * 64;
    int mrow = nblk0 + m0 + c;
    int mclamp = (mrow < N_NODES) ? mrow : (N_NODES - 1);
    const unsigned short* arow = h16 + (size_t)mclamp * D;

    f32x4 acc[4];
    #pragma unroll
    for (int t = 0; t < 4; ++t) {
        float bn = b1[n0 + t * 16 + c];
        acc[t] = (f32x4){bn, bn, bn, bn};
    }
    #pragma unroll
    for (int kk = 0; kk < 4; ++kk) {
        bf16x8 av = *(const bf16x8*)&arow[kk * 32 + q * 8];
        #pragma unroll
        for (int t = 0; t < 4; ++t) {
            bf16x8 bv = *(const bf16x8*)&wtg[(size_t)(n0 + t * 16 + c) * 128 + kk * 32 + q * 8];
            acc[t] = __builtin_amdgcn_mfma_f32_16x16x32_bf16(av, bv, acc[t], 0, 0, 0);
        }
    }
    float w2v[4];
    #pragma unroll
    for (int t = 0; t < 4; ++t) w2v[t] = w2[n0 + t * 16 + c];
    float s[4];
    #pragma unroll
    for (int r = 0; r < 4; ++r) {
        s[r] = tanhf(acc[0][r]) * w2v[0] + tanhf(acc[1][r]) * w2v[1]
             + tanhf(acc[2][r]) * w2v[2] + tanhf(acc[3][r]) * w2v[3];
    }
    #pragma unroll
    for (int o = 1; o <= 8; o <<= 1)
        #pragma unroll
        for (int r = 0; r < 4; ++r) s[r] += __shfl_xor(s[r], o);
    if (c == 0) {
        #pragma unroll
        for (int r = 0; r < 4; ++r) redg[wave & 1][m0 + q * 4 + r] = s[r];
    }
    __syncthreads();
    if ((wave & 1) == 0 && c == 0) {
        float bb2 = b2[0];
        #pragma unroll
        for (int r = 0; r < 4; ++r) {
            int m = m0 + q * 4 + r;
            int n = nblk0 + m;
            float L = redg[0][m] + redg[1][m] + bb2;
            if (n < N_NODES) { logits[n] = L; lg[m] = L; }
            else lg[m] = -INFINITY;
        }
    }
    __syncthreads();
    // wave 0: block softmax partial (max + sum of exp)
    if (wave == 0) {
        float l = (lane < GB) ? lg[lane] : -INFINITY;
        float mx = l;
        #pragma unroll
        for (int o = 32; o >= 1; o >>= 1) mx = fmaxf(mx, __shfl_xor(mx, o));
        float ex = (lane < GB && l > -INFINITY) ? expf(l - mx) : 0.f;
        #pragma unroll
        for (int o = 32; o >= 1; o >>= 1) ex += __shfl_xor(ex, o);
        if (lane == 0) gpart[blockIdx.x] = make_float2(mx, ex);
    }
}

// combine 1563 per-block partials -> global (max, 1/sum); also zero pooled
__global__ void softmax_combine_kernel(const float2* __restrict__ gpart,
                                       float* __restrict__ stats, float* __restrict__ pooled) {
    __shared__ float sbuf[16];
    int tid = threadIdx.x;   // 1024
    pooled[tid] = 0.f;
    float mx = -INFINITY;
    for (int i = tid; i < NBLK; i += 1024) mx = fmaxf(mx, gpart[i].x);
    #pragma unroll
    for (int o = 32; o >= 1; o >>= 1) mx = fmaxf(mx, __shfl_xor(mx, o));
    if ((tid & 63) == 0) sbuf[tid >> 6] = mx;
    __syncthreads();
    if (tid == 0) {
        float m = sbuf[0];
        for (int w = 1; w < 16; ++w) m = fmaxf(m, sbuf[w]);
        sbuf[0] = m;
    }
    __syncthreads();
    mx = sbuf[0];
    __syncthreads();
    float s = 0.f;
    for (int i = tid; i < NBLK; i += 1024) {
        float2 p = gpart[i];
        s += p.y * expf(p.x - mx);
    }
    #pragma unroll
    for (int o = 32; o >= 1; o >>= 1) s += __shfl_xor(s, o);
    if ((tid & 63) == 0) sbuf[tid >> 6] = s;
    __syncthreads();
    if (tid == 0) {
        float t = 0.f;
        for (int w = 0; w < 16; ++w) t += sbuf[w];
        stats[0] = mx;
        stats[1] = 1.0f / t;
    }
}

// ---------------- pool / out ----------------

#define POOL_CHUNK 128
__global__ void gate_pool_kernel(const unsigned short* __restrict__ h16,
                                 const float* __restrict__ logits,
                                 const float* __restrict__ stats, const int* __restrict__ batch,
                                 float* __restrict__ gate_out, float* __restrict__ pooled) {
    __shared__ float gs[POOL_CHUNK];
    __shared__ int bs[POOL_CHUNK];
    int n0 = blockIdx.x * POOL_CHUNK;
    int d = threadIdx.x;
    float mx = stats[0], inv = stats[1];
    int nj = n0 + d;
    if (nj < N_NODES) {
        float gv = expf(logits[nj] - mx) * inv;
        gs[d] = gv;
        bs[d] = batch[nj];
        gate_out[nj] = gv;
    }
    __syncthreads();
    int count = min(POOL_CHUNK, N_NODES - n0);
    float acc = 0.f;
    int cur = bs[0];
    int t = 0;
    for (; t + 3 < count; t += 4) {
        float h0 = bf2f(h16[(size_t)(n0 + t + 0) * D + d]);
        float h1 = bf2f(h16[(size_t)(n0 + t + 1) * D + d]);
        float h2 = bf2f(h16[(size_t)(n0 + t + 2) * D + d]);
        float h3 = bf2f(h16[(size_t)(n0 + t + 3) * D + d]);
        int b0 = bs[t], b1 = bs[t + 1], b2 = bs[t + 2], b3 = bs[t + 3];
        if (b0 != cur) { atomicAdd(&pooled[cur * D + d], acc); acc = 0.f; cur = b0; }
        acc = fmaf(h0, gs[t], acc);
        if (b1 != cur) { atomicAdd(&pooled[cur * D + d], acc); acc = 0.f; cur = b1; }
        acc = fmaf(h1, gs[t + 1], acc);
        if (b2 != cur) { atomicAdd(&pooled[cur * D + d], acc); acc = 0.f; cur = b2; }
        acc = fmaf(h2, gs[t + 2], acc);
        if (b3 != cur) { atomicAdd(&pooled[cur * D + d], acc); acc = 0.f; cur = b3; }
        acc = fmaf(h3, gs[t + 3], acc);
    }
    for (; t < count; ++t) {
        int bn = bs[t];
        if (bn != cur) { atomicAdd(&pooled[cur * D + d], acc); acc = 0.f; cur = bn; }
        acc = fmaf(bf2f(h16[(size_t)(n0 + t) * D + d]), gs[t], acc);
    }
    atomicAdd(&pooled[cur * D + d], acc);
}

__global__ void out_proj_kernel(const float* __restrict__ pooled, const float* __restrict__ w,
                                const float* __restrict__ b, const float* __restrict__ g,
                                const float* __restrict__ beta, float* __restrict__ emb) {
    __shared__ float ps[D];
    __shared__ float sbuf[2];
    int bg = blockIdx.x, d = threadIdx.x;
    ps[d] = pooled[bg * D + d];
    __syncthreads();
    float acc = b[d];
    #pragma unroll 8
    for (int k = 0; k < D; ++k) acc += ps[k] * w[k * D + d];
    float s = acc, q = acc * acc;
    #pragma unroll
    for (int o = 32; o >= 1; o >>= 1) { s += __shfl_down(s, o); q += __shfl_down(q, o); }
    if ((d & 63) == 0) { sbuf[d >> 6] = s; }
    __syncthreads();
    float fullsum = sbuf[0] + sbuf[1];
    __syncthreads();
    if ((d & 63) == 0) { sbuf[d >> 6] = q; }
    __syncthreads();
    float fullsq = sbuf[0] + sbuf[1];
    float m = fullsum * (1.0f / D);
    float var = fullsq * (1.0f / D) - m * m;
    float y = (acc - m) * rsqrtf(var + 1e-5f) * g[d] + beta[d];
    emb[bg * D + d] = gelu_exact(y);
}

extern "C" void kernel_launch(void* const* d_in, const int* in_sizes, int n_in,
                              void* d_out, int out_size, void* d_ws, size_t ws_size,
                              hipStream_t stream) {
    const float* x        = (const float*)d_in[0];
    const int*   edge     = (const int*)d_in[1];
    const int*   batch    = (const int*)d_in[2];
    const float* w_in     = (const float*)d_in[3];
    const float* b_in     = (const float*)d_in[4];
    const float* ln_in_g  = (const float*)d_in[5];
    const float* ln_in_b  = (const float*)d_in[6];
    const float* gnn_w    = (const float*)d_in[7];
    const float* gnn_b    = (const float*)d_in[8];
    const float* gnn_ln_g = (const float*)d_in[9];
    const float* gnn_ln_b = (const float*)d_in[10];
    const float* norm_g   = (const float*)d_in[11];
    const float* norm_b   = (const float*)d_in[12];
    const float* gate_w1  = (const float*)d_in[13];
    const float* gate_b1  = (const float*)d_in[14];
    const float* gate_w2  = (const float*)d_in[15];
    const float* gate_b2  = (const float*)d_in[16];
    const float* out_w    = (const float*)d_in[17];
    const float* out_b    = (const float*)d_in[18];
    const float* out_ln_g = (const float*)d_in[19];
    const float* out_ln_b = (const float*)d_in[20];

    const int* src = edge;             // edge_index[0]
    const int* dst = edge + N_EDGES;   // edge_index[1]

    float* out      = (float*)d_out;
    float* emb      = out;                               // (8,128)
    float* hA       = out + B_GRAPHS * D;                // (N,128) final h (fp32)
    float* gate_out = hA + (size_t)N_NODES * D;          // (N,)

    // workspace: bf16 ping-pong h16A/h16B; CSR temporaries deg/cursor overlaid in h16A
    unsigned short* h16A = (unsigned short*)d_ws;        // N*D bf16
    unsigned short* h16B = h16A + (size_t)N_NODES * D;   // N*D bf16
    int*   deg_i    = (int*)d_ws;                        // N      (overlay in h16A)
    int*   cursor   = (int*)d_ws + N_NODES;              // N+1    (overlay in h16A)
    int*   row_ptr  = (int*)(h16B + (size_t)N_NODES * D);// N+1
    int*   csr      = row_ptr + N_NODES + 1;             // E
    float* logits   = (float*)(csr + N_EDGES);           // N
    float* pooled   = logits + N_NODES;                  // 1024
    float* stats    = pooled + B_GRAPHS * D;             // 2
    int*   partials = (int*)(stats + 2);                 // NPART
    float2* gpart   = (float2*)(((uintptr_t)(partials + NPART) + 15) & ~(uintptr_t)15); // NBLK
    unsigned short* wt = (unsigned short*)(gpart + NBLK);
    unsigned short* wtg = wt + WT_GNN;                   // gate w1 bf16 [n=D][k=D]

    // CSR build + W prep
    zero_int_kernel<<<128, 256, 0, stream>>>(deg_i, N_NODES);
    degree_kernel<<<(N_EDGES + 255) / 256, 256, 0, stream>>>(dst, deg_i);
    scan_partials_kernel<<<NPART, SCAN_B, 0, stream>>>(deg_i, partials);
    scan_offsets_kernel<<<1, 128, 0, stream>>>(partials, row_ptr);
    scan_apply_kernel<<<NPART, SCAN_B, 0, stream>>>(deg_i, partials, row_ptr, cursor);
    fill_kernel<<<(N_EDGES + 255) / 256, 256, 0, stream>>>(src, dst, cursor, csr);
    wprep_kernel<<<(WT_ALL + 255) / 256, 256, 0, stream>>>(gnn_w, gate_w1, wt);

    // input proj -> h16B (bf16)
    input_proj_v4<<<NBLK, 256, 0, stream>>>(x, w_in, b_in, ln_in_g, ln_in_b, h16B);

    // layers: h16B -> h16A -> h16B -> (h16A + hA fp32)
    const unsigned short* hin[3]  = {h16B, h16A, h16B};
    unsigned short*       hout[3] = {h16A, h16B, h16A};
    for (int i = 0; i < NLAYER; ++i) {
        gnn_layer_v6<<<NBLK, 256, 0, stream>>>(
            hin[i], hout[i], hA, csr, row_ptr,
            wt + (size_t)i * D * 2 * D, gnn_b + i * D,
            gnn_ln_g + i * D, gnn_ln_b + i * D,
            norm_g + i * D, norm_b + i * D,
            (i < NLAYER - 1) ? 1 : 0, (i == NLAYER - 1) ? 1 : 0);
    }

    gate_v5<<<NBLK, 256, 0, stream>>>(h16A, wtg, gate_b1, gate_w2, gate_b2, logits, gpart);
    softmax_combine_kernel<<<1, 1024, 0, stream>>>(gpart, stats, pooled);
    gate_pool_kernel<<<(N_NODES + POOL_CHUNK - 1) / POOL_CHUNK, POOL_CHUNK, 0, stream>>>(
        h16A, logits, stats, batch, gate_out, pooled);
    out_proj_kernel<<<B_GRAPHS, D, 0, stream>>>(pooled, out_w, out_b, out_ln_g, out_ln_b, emb);
}

// Round 9
// 455.581 us; speedup vs baseline: 2.3364x; 1.1280x over previous
//
#include <hip/hip_runtime.h>
#include <math.h>

#define N_NODES 50000
#define N_EDGES 800000
#define F_IN 64
#define D 128
#define NLAYER 3
#define B_GRAPHS 8
#define GB 32               // nodes per block (4 waves; staging 8 nodes/wave; MFMA tiles 2x2)
#define NPW 8               // nodes per wave (staging)
#define NBLK ((N_NODES + GB - 1) / GB)            // 1563 (last block partial)
#define SCAN_B 512
#define NPART ((N_NODES + SCAN_B - 1) / SCAN_B)   // 98
#define AGP 136             // agg LDS row stride in ushorts (128 + 8 pad -> 16B-aligned rows)

typedef float f32x4 __attribute__((ext_vector_type(4)));
typedef short bf16x8 __attribute__((ext_vector_type(8)));

__device__ __forceinline__ float gelu_exact(float x) {
    return 0.5f * x * (1.0f + erff(x * 0.7071067811865476f));
}

// fp32 -> bf16 round-to-nearest-even
__device__ __forceinline__ unsigned short f2bf(float f) {
    unsigned int u = __float_as_uint(f);
    u = (u + 0x7fffu + ((u >> 16) & 1u)) >> 16;
    return (unsigned short)u;
}
__device__ __forceinline__ float bf2f(unsigned short u) {
    return __uint_as_float((unsigned int)u << 16);
}

// ---------------- CSR build ----------------

__global__ void zero_int_kernel(int* __restrict__ p, int n) {
    int i = blockIdx.x * blockDim.x + threadIdx.x;
    int stride = gridDim.x * blockDim.x;
    for (; i < n; i += stride) p[i] = 0;
}

__global__ void degree_kernel(const int* __restrict__ dst, int* __restrict__ deg) {
    int e = blockIdx.x * blockDim.x + threadIdx.x;
    if (e < N_EDGES) atomicAdd(&deg[dst[e]], 1);
}

__global__ __launch_bounds__(SCAN_B) void scan_partials_kernel(const int* __restrict__ deg,
                                                               int* __restrict__ partials) {
    __shared__ int wsum[8];
    int tid = threadIdx.x;
    int lane = tid & 63, wave = tid >> 6;
    int i = blockIdx.x * SCAN_B + tid;
    int v = (i < N_NODES) ? deg[i] : 0;
    #pragma unroll
    for (int o = 32; o >= 1; o >>= 1) v += __shfl_xor(v, o);
    if (lane == 0) wsum[wave] = v;
    __syncthreads();
    if (tid == 0) {
        int t = 0;
        #pragma unroll
        for (int w = 0; w < 8; ++w) t += wsum[w];
        partials[blockIdx.x] = t;
    }
}

__global__ void scan_offsets_kernel(int* __restrict__ partials, int* __restrict__ row_ptr) {
    __shared__ int wtot[2];
    int tid = threadIdx.x;          // 128 threads, 2 waves
    int lane = tid & 63, wave = tid >> 6;
    int v = (tid < NPART) ? partials[tid] : 0;
    int x = v;
    #pragma unroll
    for (int o = 1; o < 64; o <<= 1) { int nb = __shfl_up(x, o); if (lane >= o) x += nb; }
    if (lane == 63) wtot[wave] = x;
    __syncthreads();
    if (wave == 1) x += wtot[0];
    if (tid < NPART) partials[tid] = x - v;       // exclusive
    if (tid == 127) row_ptr[N_NODES] = x;         // grand total
}

__global__ __launch_bounds__(SCAN_B) void scan_apply_kernel(const int* __restrict__ deg,
        const int* __restrict__ partials, int* __restrict__ row_ptr, int* __restrict__ cursor) {
    __shared__ int wsum[8];
    int tid = threadIdx.x;
    int lane = tid & 63, wave = tid >> 6;
    int i = blockIdx.x * SCAN_B + tid;
    int v = (i < N_NODES) ? deg[i] : 0;
    int x = v;
    #pragma unroll
    for (int o = 1; o < 64; o <<= 1) { int nb = __shfl_up(x, o); if (lane >= o) x += nb; }
    if (lane == 63) wsum[wave] = x;
    __syncthreads();
    int waveoff = 0;
    #pragma unroll
    for (int w = 0; w < 8; ++w) waveoff += (w < wave) ? wsum[w] : 0;
    int excl = partials[blockIdx.x] + waveoff + x - v;
    if (i < N_NODES) { row_ptr[i] = excl; cursor[i] = excl; }
}

__global__ void fill_kernel(const int* __restrict__ src, const int* __restrict__ dst,
                            int* __restrict__ cursor, int* __restrict__ csr) {
    int e = blockIdx.x * blockDim.x + threadIdx.x;
    if (e < N_EDGES) {
        int t = dst[e];
        int pos = atomicAdd(&cursor[t], 1);
        csr[pos] = src[e];
    }
}

// W prep: gnn_w -> wt bf16 [L][n=D][k=2D]; gate_w1 -> [n=D][k=D]; w_in -> [n=D][k=F_IN]
// block 0 also zeroes pooled (1024 floats)
#define WT_GNN (NLAYER * D * 2 * D)
#define WT_G1  (WT_GNN + D * D)
#define WT_ALL (WT_G1 + D * F_IN)
__global__ void wprep_kernel(const float* __restrict__ gnn_w, const float* __restrict__ gate_w1,
                             const float* __restrict__ w_in, unsigned short* __restrict__ wt,
                             float* __restrict__ pooled) {
    int idx = blockIdx.x * 256 + threadIdx.x;
    if (blockIdx.x == 0) {
        #pragma unroll
        for (int i = 0; i < 4; ++i) pooled[threadIdx.x + i * 256] = 0.f;
    }
    if (idx >= WT_ALL) return;
    if (idx < WT_GNN) {
        int l = idx / (D * 2 * D);
        int rem = idx - l * (D * 2 * D);
        int n = rem / (2 * D);
        int k = rem - n * (2 * D);
        wt[idx] = f2bf(gnn_w[(size_t)l * 2 * D * D + (size_t)k * D + n]);
    } else if (idx < WT_G1) {
        int rem = idx - WT_GNN;
        int n = rem / D;
        int k = rem - n * D;
        wt[idx] = f2bf(gate_w1[(size_t)k * D + n]);
    } else {
        int rem = idx - WT_G1;
        int n = rem / F_IN;
        int k = rem - n * F_IN;
        wt[idx] = f2bf(w_in[(size_t)k * D + n]);
    }
}

// ---------------- input proj v5: MFMA, x converted fp32->bf16 in-register ----------------

__global__ __launch_bounds__(256) void input_proj_v5(
        const float* __restrict__ x, const unsigned short* __restrict__ wti,
        const float* __restrict__ b, const float* __restrict__ gam,
        const float* __restrict__ bet, unsigned short* __restrict__ h16) {
    __shared__ float2 red[2][GB];
    int tid = threadIdx.x;
    int wave = tid >> 6, lane = tid & 63;
    int nblk0 = blockIdx.x * GB;
    int q = lane >> 4, c = lane & 15;
    int m0 = (wave >> 1) * 16;
    int n0 = (wave & 1) * 64;
    int mrow = nblk0 + m0 + c;
    int mclamp = (mrow < N_NODES) ? mrow : (N_NODES - 1);
    const float* xr = x + (size_t)mclamp * F_IN;

    f32x4 acc[4];
    #pragma unroll
    for (int t = 0; t < 4; ++t) {
        float bn = b[n0 + t * 16 + c];
        acc[t] = (f32x4){bn, bn, bn, bn};
    }
    #pragma unroll
    for (int kk = 0; kk < 2; ++kk) {
        float4 a0 = *(const float4*)&xr[kk * 32 + q * 8];
        float4 a1 = *(const float4*)&xr[kk * 32 + q * 8 + 4];
        bf16x8 av;
        av[0] = (short)f2bf(a0.x); av[1] = (short)f2bf(a0.y);
        av[2] = (short)f2bf(a0.z); av[3] = (short)f2bf(a0.w);
        av[4] = (short)f2bf(a1.x); av[5] = (short)f2bf(a1.y);
        av[6] = (short)f2bf(a1.z); av[7] = (short)f2bf(a1.w);
        #pragma unroll
        for (int t = 0; t < 4; ++t) {
            bf16x8 bv = *(const bf16x8*)&wti[(size_t)(n0 + t * 16 + c) * F_IN + kk * 32 + q * 8];
            acc[t] = __builtin_amdgcn_mfma_f32_16x16x32_bf16(av, bv, acc[t], 0, 0, 0);
        }
    }
    // LN over z, then gelu.  C-layout: lane (q,c) holds nodes m0+q*4+r, dims n0+t*16+c
    float s[4], sq[4];
    #pragma unroll
    for (int r = 0; r < 4; ++r) {
        s[r] = acc[0][r] + acc[1][r] + acc[2][r] + acc[3][r];
        sq[r] = acc[0][r] * acc[0][r] + acc[1][r] * acc[1][r]
              + acc[2][r] * acc[2][r] + acc[3][r] * acc[3][r];
    }
    #pragma unroll
    for (int o = 1; o <= 8; o <<= 1)
        #pragma unroll
        for (int r = 0; r < 4; ++r) { s[r] += __shfl_xor(s[r], o); sq[r] += __shfl_xor(sq[r], o); }
    if (c == 0) {
        #pragma unroll
        for (int r = 0; r < 4; ++r) red[wave & 1][m0 + q * 4 + r] = make_float2(s[r], sq[r]);
    }
    __syncthreads();
    float gv[4], bv2[4];
    #pragma unroll
    for (int t = 0; t < 4; ++t) {
        int nn = n0 + t * 16 + c;
        gv[t] = gam[nn]; bv2[t] = bet[nn];
    }
    #pragma unroll
    for (int r = 0; r < 4; ++r) {
        int m = m0 + q * 4 + r;
        int n = nblk0 + m;
        float2 p0 = red[0][m], p1 = red[1][m];
        float mean = (p0.x + p1.x) * (1.0f / D);
        float msq  = (p0.y + p1.y) * (1.0f / D);
        float istd = rsqrtf(msq - mean * mean + 1e-5f);
        if (n < N_NODES) {
            #pragma unroll
            for (int t = 0; t < 4; ++t) {
                int nn = n0 + t * 16 + c;
                float y = (acc[t][r] - mean) * istd * gv[t] + bv2[t];
                h16[(size_t)n * D + nn] = f2bf(gelu_exact(y));
            }
        }
    }
}

// ---------------- GNN layer v7: LDS edge-index staging, 8-deep row loads, MFMA ----------
// DO_GATE=1 (last layer): fuses the attention-gate MLP + logits + per-block softmax partials.

__device__ __forceinline__ void acc_row(float acc[8], bf16x8 v) {
    #pragma unroll
    for (int i = 0; i < 8; ++i)
        acc[i] += __uint_as_float(((unsigned int)(unsigned short)v[i]) << 16);
}

template<int DO_GATE>
__global__ __launch_bounds__(256) void gnn_layer_v7(
        const unsigned short* __restrict__ h16_in, unsigned short* __restrict__ h16_out,
        float* __restrict__ hf_out,
        const int* __restrict__ csr, const int* __restrict__ rp,
        const unsigned short* __restrict__ wt,   // [n=D][k=2D] bf16
        const float* __restrict__ bias,
        const float* __restrict__ ln1g, const float* __restrict__ ln1b,
        const float* __restrict__ ln2g, const float* __restrict__ ln2b,
        int residual, int write_f32,
        const unsigned short* __restrict__ wtg,  // gate w1 [n=D][k=D] bf16 (DO_GATE)
        const float* __restrict__ gb1, const float* __restrict__ gw2,
        const float* __restrict__ gb2,
        float* __restrict__ logits, float2* __restrict__ gpart) {
    __shared__ int rps[GB + 1];
    __shared__ int eidx[GB][32];                // 4 KB
    __shared__ unsigned short aggb[GB][AGP];    // 8.7 KB (agg half; reused for gate staging)
    __shared__ float2 red1[2][GB];
    __shared__ float2 red2[2][GB];
    __shared__ float redg[2][GB];
    __shared__ float lg[GB];

    int tid = threadIdx.x;
    int wave = tid >> 6, lane = tid & 63;
    int nblk0 = blockIdx.x * GB;
    int gbase = wave * NPW;

    // phase 1: row_ptr slice -> LDS
    if (tid < GB + 1) {
        int n = nblk0 + tid;
        if (n > N_NODES) n = N_NODES;
        rps[tid] = rp[n];
    }
    __syncthreads();
    // phase 2: cooperative edge-index fill (clamped slots), one coalesced pass
    #pragma unroll
    for (int k2 = 0; k2 < 4; ++k2) {
        int f = tid + k2 * 256;
        int g = f >> 5, sl = f & 31;
        int beg = rps[g], end = rps[g + 1];
        int ee = beg + sl;
        int ci = (ee < end) ? ee : ((end > beg) ? (end - 1) : 0);
        eidx[g][sl] = csr[ci];
    }
    __syncthreads();

    // phase 3: gather. lane: er = edge slot group (0..3), dg = dim group (0..15)
    {
        int er = lane >> 4, dg = lane & 15;
        #pragma unroll
        for (int j = 0; j < NPW; ++j) {
            int g = gbase + j;
            int beg = rps[g], end = rps[g + 1];
            int deg = end - beg;
            int id8[8];
            #pragma unroll
            for (int t = 0; t < 8; ++t) id8[t] = eidx[g][er + 4 * t];
            bf16x8 v[8];
            #pragma unroll
            for (int t = 0; t < 8; ++t)
                v[t] = *(const bf16x8*)&h16_in[(size_t)id8[t] * D + dg * 8];
            float acc[8];
            #pragma unroll
            for (int i = 0; i < 8; ++i) acc[i] = 0.f;
            #pragma unroll
            for (int t = 0; t < 8; ++t)
                if (beg + er + 4 * t < end) acc_row(acc, v[t]);
            if (deg > 32) {                     // rare tail
                for (int ee = beg + er + 32; ee < end; ee += 4) {
                    bf16x8 vv = *(const bf16x8*)&h16_in[(size_t)csr[ee] * D + dg * 8];
                    acc_row(acc, vv);
                }
            }
            #pragma unroll
            for (int i = 0; i < 8; ++i) {
                acc[i] += __shfl_xor(acc[i], 16);
                acc[i] += __shfl_xor(acc[i], 32);
            }
            float inv = 1.0f / fmaxf((float)deg, 1.0f);
            if (er == 0) {
                bf16x8 o;
                #pragma unroll
                for (int i = 0; i < 8; ++i) o[i] = (short)f2bf(acc[i] * inv);
                *(bf16x8*)&aggb[g][dg * 8] = o;
            }
        }
    }
    __syncthreads();

    // ---- MFMA GEMM: wave tile = 16 nodes x 64 dims; K=256 (128 self global, 128 agg LDS)
    int q = lane >> 4, c = lane & 15;
    int m0 = (wave >> 1) * 16;
    int n0 = (wave & 1) * 64;
    int mrow = nblk0 + m0 + c;
    int mclamp = (mrow < N_NODES) ? mrow : (N_NODES - 1);
    const unsigned short* arow = h16_in + (size_t)mclamp * D;

    f32x4 acc[4];
    #pragma unroll
    for (int t = 0; t < 4; ++t) {
        float bn = bias[n0 + t * 16 + c];
        acc[t] = (f32x4){bn, bn, bn, bn};
    }
    #pragma unroll
    for (int kk = 0; kk < 4; ++kk) {
        bf16x8 av = *(const bf16x8*)&arow[kk * 32 + q * 8];
        #pragma unroll
        for (int t = 0; t < 4; ++t) {
            bf16x8 bv = *(const bf16x8*)&wt[(size_t)(n0 + t * 16 + c) * 256 + kk * 32 + q * 8];
            acc[t] = __builtin_amdgcn_mfma_f32_16x16x32_bf16(av, bv, acc[t], 0, 0, 0);
        }
    }
    #pragma unroll
    for (int kk = 0; kk < 4; ++kk) {
        bf16x8 av = *(const bf16x8*)&aggb[m0 + c][kk * 32 + q * 8];
        #pragma unroll
        for (int t = 0; t < 4; ++t) {
            bf16x8 bv = *(const bf16x8*)&wt[(size_t)(n0 + t * 16 + c) * 256 + 128 + kk * 32 + q * 8];
            acc[t] = __builtin_amdgcn_mfma_f32_16x16x32_bf16(av, bv, acc[t], 0, 0, 0);
        }
    }

    // ---- epilogue: gelu -> LN1 -> LN2 -> (gelu+residual) in C-layout
    float xv[4][4];
    #pragma unroll
    for (int t = 0; t < 4; ++t)
        #pragma unroll
        for (int r = 0; r < 4; ++r) xv[t][r] = gelu_exact(acc[t][r]);

    float s[4], sq[4];
    #pragma unroll
    for (int r = 0; r < 4; ++r) {
        s[r] = xv[0][r] + xv[1][r] + xv[2][r] + xv[3][r];
        sq[r] = xv[0][r] * xv[0][r] + xv[1][r] * xv[1][r] + xv[2][r] * xv[2][r] + xv[3][r] * xv[3][r];
    }
    #pragma unroll
    for (int o = 1; o <= 8; o <<= 1)
        #pragma unroll
        for (int r = 0; r < 4; ++r) { s[r] += __shfl_xor(s[r], o); sq[r] += __shfl_xor(sq[r], o); }
    int nh = wave & 1;
    if (c == 0) {
        #pragma unroll
        for (int r = 0; r < 4; ++r) red1[nh][m0 + q * 4 + r] = make_float2(s[r], sq[r]);
    }
    __syncthreads();

    float g1v[4], b1v[4], g2v[4], b2v[4];
    #pragma unroll
    for (int t = 0; t < 4; ++t) {
        int nn = n0 + t * 16 + c;
        g1v[t] = ln1g[nn]; b1v[t] = ln1b[nn];
        g2v[t] = ln2g[nn]; b2v[t] = ln2b[nn];
    }

    float y1[4][4];
    #pragma unroll
    for (int r = 0; r < 4; ++r) {
        int m = m0 + q * 4 + r;
        float2 p0 = red1[0][m], p1 = red1[1][m];
        float mean = (p0.x + p1.x) * (1.0f / D);
        float msq  = (p0.y + p1.y) * (1.0f / D);
        float istd = rsqrtf(msq - mean * mean + 1e-5f);
        #pragma unroll
        for (int t = 0; t < 4; ++t)
            y1[t][r] = (xv[t][r] - mean) * istd * g1v[t] + b1v[t];
    }

    #pragma unroll
    for (int r = 0; r < 4; ++r) {
        s[r] = y1[0][r] + y1[1][r] + y1[2][r] + y1[3][r];
        sq[r] = y1[0][r] * y1[0][r] + y1[1][r] * y1[1][r] + y1[2][r] * y1[2][r] + y1[3][r] * y1[3][r];
    }
    #pragma unroll
    for (int o = 1; o <= 8; o <<= 1)
        #pragma unroll
        for (int r = 0; r < 4; ++r) { s[r] += __shfl_xor(s[r], o); sq[r] += __shfl_xor(sq[r], o); }
    if (c == 0) {
        #pragma unroll
        for (int r = 0; r < 4; ++r) red2[nh][m0 + q * 4 + r] = make_float2(s[r], sq[r]);
    }
    __syncthreads();

    #pragma unroll
    for (int r = 0; r < 4; ++r) {
        int m = m0 + q * 4 + r;
        int n = nblk0 + m;
        float2 p0 = red2[0][m], p1 = red2[1][m];
        float mean = (p0.x + p1.x) * (1.0f / D);
        float msq  = (p0.y + p1.y) * (1.0f / D);
        float istd = rsqrtf(msq - mean * mean + 1e-5f);
        #pragma unroll
        for (int t = 0; t < 4; ++t) {
            int nn = n0 + t * 16 + c;
            float y2 = (y1[t][r] - mean) * istd * g2v[t] + b2v[t];
            float o = residual ? (gelu_exact(y2) + bf2f(h16_in[(size_t)n * D + nn])) : y2;
            if (n < N_NODES) {
                h16_out[(size_t)n * D + nn] = f2bf(o);
                if (write_f32) hf_out[(size_t)n * D + nn] = o;
            }
            if (DO_GATE) aggb[m][nn] = f2bf(o);   // gate staging (aggb free after GEMM)
        }
    }

    if (DO_GATE) {
        __syncthreads();
        // gate MFMA: A from aggb (final h, bf16), B = wtg; K=128
        f32x4 gacc[4];
        #pragma unroll
        for (int t = 0; t < 4; ++t) {
            float bn = gb1[n0 + t * 16 + c];
            gacc[t] = (f32x4){bn, bn, bn, bn};
        }
        #pragma unroll
        for (int kk = 0; kk < 4; ++kk) {
            bf16x8 av = *(const bf16x8*)&aggb[m0 + c][kk * 32 + q * 8];
            #pragma unroll
            for (int t = 0; t < 4; ++t) {
                bf16x8 bv = *(const bf16x8*)&wtg[(size_t)(n0 + t * 16 + c) * 128 + kk * 32 + q * 8];
                gacc[t] = __builtin_amdgcn_mfma_f32_16x16x32_bf16(av, bv, gacc[t], 0, 0, 0);
            }
        }
        float w2v[4];
        #pragma unroll
        for (int t = 0; t < 4; ++t) w2v[t] = gw2[n0 + t * 16 + c];
        float gs[4];
        #pragma unroll
        for (int r = 0; r < 4; ++r) {
            gs[r] = tanhf(gacc[0][r]) * w2v[0] + tanhf(gacc[1][r]) * w2v[1]
                  + tanhf(gacc[2][r]) * w2v[2] + tanhf(gacc[3][r]) * w2v[3];
        }
        #pragma unroll
        for (int o = 1; o <= 8; o <<= 1)
            #pragma unroll
            for (int r = 0; r < 4; ++r) gs[r] += __shfl_xor(gs[r], o);
        if (c == 0) {
            #pragma unroll
            for (int r = 0; r < 4; ++r) redg[nh][m0 + q * 4 + r] = gs[r];
        }
        __syncthreads();
        if ((wave & 1) == 0 && c == 0) {
            float bb2 = gb2[0];
            #pragma unroll
            for (int r = 0; r < 4; ++r) {
                int m = m0 + q * 4 + r;
                int n = nblk0 + m;
                float L = redg[0][m] + redg[1][m] + bb2;
                if (n < N_NODES) { logits[n] = L; lg[m] = L; }
                else lg[m] = -INFINITY;
            }
        }
        __syncthreads();
        if (wave == 0) {
            float l = (lane < GB) ? lg[lane] : -INFINITY;
            float mx = l;
            #pragma unroll
            for (int o = 32; o >= 1; o >>= 1) mx = fmaxf(mx, __shfl_xor(mx, o));
            float ex = (lane < GB && l > -INFINITY) ? expf(l - mx) : 0.f;
            #pragma unroll
            for (int o = 32; o >= 1; o >>= 1) ex += __shfl_xor(ex, o);
            if (lane == 0) gpart[blockIdx.x] = make_float2(mx, ex);
        }
    }
}

// ---------------- pool (stats folded in) / out ----------------

#define POOL_CHUNK 128
__global__ __launch_bounds__(POOL_CHUNK) void gate_pool_v2(
        const unsigned short* __restrict__ h16, const float* __restrict__ logits,
        const float2* __restrict__ gpart, const int* __restrict__ batch,
        float* __restrict__ gate_out, float* __restrict__ pooled) {
    __shared__ float sb[4];
    __shared__ float gs[POOL_CHUNK];
    __shared__ int bs[POOL_CHUNK];
    int d = threadIdx.x;
    int lane = d & 63, wv = d >> 6;
    // global softmax stats from per-block partials (12.5 KB, L2-hot)
    float mx = -INFINITY;
    for (int i = d; i < NBLK; i += POOL_CHUNK) mx = fmaxf(mx, gpart[i].x);
    #pragma unroll
    for (int o = 32; o >= 1; o >>= 1) mx = fmaxf(mx, __shfl_xor(mx, o));
    if (lane == 0) sb[wv] = mx;
    __syncthreads();
    mx = fmaxf(sb[0], sb[1]);
    float ssum = 0.f;
    for (int i = d; i < NBLK; i += POOL_CHUNK) {
        float2 p = gpart[i];
        ssum += p.y * expf(p.x - mx);
    }
    #pragma unroll
    for (int o = 32; o >= 1; o >>= 1) ssum += __shfl_xor(ssum, o);
    if (lane == 0) sb[2 + wv] = ssum;
    __syncthreads();
    float inv = 1.0f / (sb[2] + sb[3]);

    int n0 = blockIdx.x * POOL_CHUNK;
    int nj = n0 + d;
    if (nj < N_NODES) {
        float gv = expf(logits[nj] - mx) * inv;
        gs[d] = gv;
        bs[d] = batch[nj];
        gate_out[nj] = gv;
    }
    __syncthreads();
    int count = min(POOL_CHUNK, N_NODES - n0);
    float acc = 0.f;
    int cur = bs[0];
    int t = 0;
    for (; t + 3 < count; t += 4) {
        float h0 = bf2f(h16[(size_t)(n0 + t + 0) * D + d]);
        float h1 = bf2f(h16[(size_t)(n0 + t + 1) * D + d]);
        float h2 = bf2f(h16[(size_t)(n0 + t + 2) * D + d]);
        float h3 = bf2f(h16[(size_t)(n0 + t + 3) * D + d]);
        int b0 = bs[t], b1 = bs[t + 1], b2 = bs[t + 2], b3 = bs[t + 3];
        if (b0 != cur) { atomicAdd(&pooled[cur * D + d], acc); acc = 0.f; cur = b0; }
        acc = fmaf(h0, gs[t], acc);
        if (b1 != cur) { atomicAdd(&pooled[cur * D + d], acc); acc = 0.f; cur = b1; }
        acc = fmaf(h1, gs[t + 1], acc);
        if (b2 != cur) { atomicAdd(&pooled[cur * D + d], acc); acc = 0.f; cur = b2; }
        acc = fmaf(h2, gs[t + 2], acc);
        if (b3 != cur) { atomicAdd(&pooled[cur * D + d], acc); acc = 0.f; cur = b3; }
        acc = fmaf(h3, gs[t + 3], acc);
    }
    for (; t < count; ++t) {
        int bn = bs[t];
        if (bn != cur) { atomicAdd(&pooled[cur * D + d], acc); acc = 0.f; cur = bn; }
        acc = fmaf(bf2f(h16[(size_t)(n0 + t) * D + d]), gs[t], acc);
    }
    atomicAdd(&pooled[cur * D + d], acc);
}

__global__ void out_proj_kernel(const float* __restrict__ pooled, const float* __restrict__ w,
                                const float* __restrict__ b, const float* __restrict__ g,
                                const float* __restrict__ beta, float* __restrict__ emb) {
    __shared__ float ps[D];
    __shared__ float sbuf[2];
    int bg = blockIdx.x, d = threadIdx.x;
    ps[d] = pooled[bg * D + d];
    __syncthreads();
    float acc = b[d];
    #pragma unroll 8
    for (int k = 0; k < D; ++k) acc += ps[k] * w[k * D + d];
    float s = acc, q = acc * acc;
    #pragma unroll
    for (int o = 32; o >= 1; o >>= 1) { s += __shfl_down(s, o); q += __shfl_down(q, o); }
    if ((d & 63) == 0) { sbuf[d >> 6] = s; }
    __syncthreads();
    float fullsum = sbuf[0] + sbuf[1];
    __syncthreads();
    if ((d & 63) == 0) { sbuf[d >> 6] = q; }
    __syncthreads();
    float fullsq = sbuf[0] + sbuf[1];
    float m = fullsum * (1.0f / D);
    float var = fullsq * (1.0f / D) - m * m;
    float y = (acc - m) * rsqrtf(var + 1e-5f) * g[d] + beta[d];
    emb[bg * D + d] = gelu_exact(y);
}

extern "C" void kernel_launch(void* const* d_in, const int* in_sizes, int n_in,
                              void* d_out, int out_size, void* d_ws, size_t ws_size,
                              hipStream_t stream) {
    const float* x        = (const float*)d_in[0];
    const int*   edge     = (const int*)d_in[1];
    const int*   batch    = (const int*)d_in[2];
    const float* w_in     = (const float*)d_in[3];
    const float* b_in     = (const float*)d_in[4];
    const float* ln_in_g  = (const float*)d_in[5];
    const float* ln_in_b  = (const float*)d_in[6];
    const float* gnn_w    = (const float*)d_in[7];
    const float* gnn_b    = (const float*)d_in[8];
    const float* gnn_ln_g = (const float*)d_in[9];
    const float* gnn_ln_b = (const float*)d_in[10];
    const float* norm_g   = (const float*)d_in[11];
    const float* norm_b   = (const float*)d_in[12];
    const float* gate_w1  = (const float*)d_in[13];
    const float* gate_b1  = (const float*)d_in[14];
    const float* gate_w2  = (const float*)d_in[15];
    const float* gate_b2  = (const float*)d_in[16];
    const float* out_w    = (const float*)d_in[17];
    const float* out_b    = (const float*)d_in[18];
    const float* out_ln_g = (const float*)d_in[19];
    const float* out_ln_b = (const float*)d_in[20];

    const int* src = edge;             // edge_index[0]
    const int* dst = edge + N_EDGES;   // edge_index[1]

    float* out      = (float*)d_out;
    float* emb      = out;                               // (8,128)
    float* hA       = out + B_GRAPHS * D;                // (N,128) final h (fp32)
    float* gate_out = hA + (size_t)N_NODES * D;          // (N,)

    // workspace: bf16 ping-pong h16A/h16B; CSR temporaries deg/cursor overlaid in h16A
    unsigned short* h16A = (unsigned short*)d_ws;        // N*D bf16
    unsigned short* h16B = h16A + (size_t)N_NODES * D;   // N*D bf16
    int*   deg_i    = (int*)d_ws;                        // N      (overlay in h16A)
    int*   cursor   = (int*)d_ws + N_NODES;              // N+1    (overlay in h16A)
    int*   row_ptr  = (int*)(h16B + (size_t)N_NODES * D);// N+1
    int*   csr      = row_ptr + N_NODES + 1;             // E
    float* logits   = (float*)(csr + N_EDGES);           // N
    float* pooled   = logits + N_NODES;                  // 1024
    int*   partials = (int*)(pooled + B_GRAPHS * D);     // NPART
    float2* gpart   = (float2*)(((uintptr_t)(partials + NPART) + 15) & ~(uintptr_t)15); // NBLK
    unsigned short* wt  = (unsigned short*)(gpart + NBLK);
    unsigned short* wtg = wt + WT_GNN;                   // gate w1 bf16 [n=D][k=D]
    unsigned short* wti = wt + WT_G1;                    // w_in bf16 [n=D][k=F_IN]

    // CSR build + W prep (+pooled zero)
    zero_int_kernel<<<128, 256, 0, stream>>>(deg_i, N_NODES);
    degree_kernel<<<(N_EDGES + 255) / 256, 256, 0, stream>>>(dst, deg_i);
    scan_partials_kernel<<<NPART, SCAN_B, 0, stream>>>(deg_i, partials);
    scan_offsets_kernel<<<1, 128, 0, stream>>>(partials, row_ptr);
    scan_apply_kernel<<<NPART, SCAN_B, 0, stream>>>(deg_i, partials, row_ptr, cursor);
    fill_kernel<<<(N_EDGES + 255) / 256, 256, 0, stream>>>(src, dst, cursor, csr);
    wprep_kernel<<<(WT_ALL + 255) / 256, 256, 0, stream>>>(gnn_w, gate_w1, w_in, wt, pooled);

    // input proj (MFMA) -> h16B
    input_proj_v5<<<NBLK, 256, 0, stream>>>(x, wti, b_in, ln_in_g, ln_in_b, h16B);

    // layers: h16B -> h16A -> h16B -> (h16A + hA fp32 + gate fused)
    gnn_layer_v7<0><<<NBLK, 256, 0, stream>>>(
        h16B, h16A, hA, csr, row_ptr, wt, gnn_b,
        gnn_ln_g, gnn_ln_b, norm_g, norm_b, 1, 0,
        nullptr, nullptr, nullptr, nullptr, nullptr, nullptr);
    gnn_layer_v7<0><<<NBLK, 256, 0, stream>>>(
        h16A, h16B, hA, csr, row_ptr, wt + (size_t)1 * D * 2 * D, gnn_b + D,
        gnn_ln_g + D, gnn_ln_b + D, norm_g + D, norm_b + D, 1, 0,
        nullptr, nullptr, nullptr, nullptr, nullptr, nullptr);
    gnn_layer_v7<1><<<NBLK, 256, 0, stream>>>(
        h16B, h16A, hA, csr, row_ptr, wt + (size_t)2 * D * 2 * D, gnn_b + 2 * D,
        gnn_ln_g + 2 * D, gnn_ln_b + 2 * D, norm_g + 2 * D, norm_b + 2 * D, 0, 1,
        wtg, gate_b1, gate_w2, gate_b2, logits, gpart);

    gate_pool_v2<<<(N_NODES + POOL_CHUNK - 1) / POOL_CHUNK, POOL_CHUNK, 0, stream>>>(
        h16A, logits, gpart, batch, gate_out, pooled);
    out_proj_kernel<<<B_GRAPHS, D, 0, stream>>>(pooled, out_w, out_b, out_ln_g, out_ln_b, emb);
}